// Round 1
// baseline (3186.886 us; speedup 1.0000x reference)
//
#include <hip/hip_runtime.h>

typedef unsigned short ushort_t;
typedef __attribute__((ext_vector_type(4))) float f32x4;
typedef __attribute__((ext_vector_type(8))) __bf16 bf16x8;
typedef __attribute__((ext_vector_type(8))) unsigned short u16x8;
typedef __attribute__((ext_vector_type(4))) unsigned short u16x4;

__device__ __forceinline__ unsigned short f2bf(float f) {
  union { float f; unsigned int u; } v; v.f = f;
  unsigned int u = v.u;
  u += 0x7fffu + ((u >> 16) & 1u);   // round-to-nearest-even
  return (unsigned short)(u >> 16);
}

__device__ __forceinline__ void gload16(ushort_t* lds, const ushort_t* g) {
  __builtin_amdgcn_global_load_lds(
      (const __attribute__((address_space(1))) unsigned int*)g,
      (__attribute__((address_space(3))) unsigned int*)lds, 16, 0, 0);
}

// ---------------- weight transpose + f32->bf16 convert:  in [R][C] f32 -> out [C][R] bf16
__global__ __launch_bounds__(256)
void transpose_w(const float* __restrict__ in, ushort_t* __restrict__ out, int R, int C) {
  __shared__ float tile[32][33];
  const int t = threadIdx.x;
  const int tx = t & 31, ty = t >> 5;
  const int r0 = blockIdx.x * 32, c0 = blockIdx.y * 32;
#pragma unroll
  for (int i = 0; i < 4; ++i)
    tile[ty + 8 * i][tx] = in[(size_t)(r0 + ty + 8 * i) * C + c0 + tx];
  __syncthreads();
#pragma unroll
  for (int i = 0; i < 4; ++i)
    out[(size_t)(c0 + ty + 8 * i) * R + r0 + tx] = f2bf(tile[tx][ty + 8 * i]);
}

// ---------------- scatter-mean accumulate (fp32 atomics)
__global__ __launch_bounds__(256)
void scatter_add_kernel(const float4* __restrict__ ea, const int* __restrict__ col,
                        float* __restrict__ seg, float* __restrict__ cnt, int E) {
  long idx = (long)blockIdx.x * 256 + threadIdx.x;  // one float4 per thread
  if (idx >= (long)E * 64) return;
  int e = (int)(idx >> 6);
  int c4 = (int)(idx & 63);
  int d = col[e];
  float4 v = ea[idx];
  float* dst = seg + (size_t)d * 256 + c4 * 4;
  atomicAdd(dst + 0, v.x);
  atomicAdd(dst + 1, v.y);
  atomicAdd(dst + 2, v.z);
  atomicAdd(dst + 3, v.w);
  if (c4 == 0) atomicAdd(cnt + d, 1.0f);
}

// ---------------- h0 = concat(agg, x) -> bf16 into hcat[:, 2048:2560]
__global__ __launch_bounds__(256)
void build_h0(const float* __restrict__ seg, const float* __restrict__ cnt,
              const float* __restrict__ x, ushort_t* __restrict__ hcat, int N) {
  int idx = blockIdx.x * 256 + threadIdx.x;
  if (idx >= N * 128) return;
  int row = idx >> 7;
  int c = (idx & 127) * 4;
  float4 v;
  if (c < 256) {
    v = *(const float4*)(seg + (size_t)row * 256 + c);
    float inv = 1.f / fmaxf(cnt[row], 1.f);
    v.x *= inv; v.y *= inv; v.z *= inv; v.w *= inv;
  } else {
    v = *(const float4*)(x + (size_t)row * 256 + (c - 256));
  }
  u16x4 o;
  o[0] = f2bf(v.x); o[1] = f2bf(v.y); o[2] = f2bf(v.z); o[3] = f2bf(v.w);
  *(u16x4*)(hcat + (size_t)row * 2560 + 2048 + c) = o;
}

// ---------------- LayerNorm over h4 [N][2048] f32 -> bf16 into hcat[:, 0:2048]
__global__ __launch_bounds__(256)
void ln_kernel(const float* __restrict__ h4, const float* __restrict__ g,
               const float* __restrict__ b, ushort_t* __restrict__ hcat) {
  const int row = blockIdx.x;
  const int t = threadIdx.x;
  const float* p = h4 + (size_t)row * 2048;
  float4 v0 = *(const float4*)(p + t * 8);
  float4 v1 = *(const float4*)(p + t * 8 + 4);
  float vv[8] = {v0.x, v0.y, v0.z, v0.w, v1.x, v1.y, v1.z, v1.w};
  float s = 0.f, ss = 0.f;
#pragma unroll
  for (int j = 0; j < 8; ++j) { s += vv[j]; ss += vv[j] * vv[j]; }
#pragma unroll
  for (int o = 32; o > 0; o >>= 1) {
    s += __shfl_xor(s, o);
    ss += __shfl_xor(ss, o);
  }
  __shared__ float red[8];
  int w = t >> 6, l = t & 63;
  if (l == 0) { red[w] = s; red[4 + w] = ss; }
  __syncthreads();
  s = red[0] + red[1] + red[2] + red[3];
  ss = red[4] + red[5] + red[6] + red[7];
  const float mu = s * (1.f / 2048.f);
  const float var = ss * (1.f / 2048.f) - mu * mu;
  const float rs = rsqrtf(var + 1e-5f);
  float4 g0 = *(const float4*)(g + t * 8);
  float4 g1 = *(const float4*)(g + t * 8 + 4);
  float4 b0 = *(const float4*)(b + t * 8);
  float4 b1 = *(const float4*)(b + t * 8 + 4);
  float gg[8] = {g0.x, g0.y, g0.z, g0.w, g1.x, g1.y, g1.z, g1.w};
  float bb[8] = {b0.x, b0.y, b0.z, b0.w, b1.x, b1.y, b1.z, b1.w};
  u16x8 o8;
#pragma unroll
  for (int j = 0; j < 8; ++j) o8[j] = f2bf((vv[j] - mu) * rs * gg[j] + bb[j]);
  *(u16x8*)(hcat + (size_t)row * 2560 + t * 8) = o8;
}

// ---------------- bf16 MFMA GEMM: C[M][Nc] = A[M][K] @ Bt[Nc][K]^T + bias, m97 structure
// BM=BN=128, BK=32, 256 threads = 4 waves, each wave 64x64 (4x4 of 16x16x32)
template <int RELU, int OUTBF>
__global__ __launch_bounds__(256)
void gemm_bt(const ushort_t* __restrict__ A, int lda,
             const ushort_t* __restrict__ Bt,
             const float* __restrict__ bias,
             void* __restrict__ Cout, int ldc, int M, int K) {
  __shared__ __align__(16) ushort_t sA[128 * 32];
  __shared__ __align__(16) ushort_t sB[128 * 32];
  const int t = threadIdx.x;
  const int row0 = blockIdx.x * 128;
  const int col0 = blockIdx.y * 128;
  const int w = t >> 6, l = t & 63;
  const int wr = (w >> 1) * 64, wc = (w & 1) * 64;
  const int lr = l & 15, lk = l >> 4;

  // staging: each thread owns two 16B chunks of A-tile and two of B-tile
  const int sr = t >> 2;           // tile row 0..63
  const int sk = (t & 3) * 8;      // k offset
  int ar1 = row0 + sr;       if (ar1 > M - 1) ar1 = M - 1;
  int ar2 = row0 + 64 + sr;  if (ar2 > M - 1) ar2 = M - 1;
  const ushort_t* pa1 = A + (size_t)ar1 * lda + sk;
  const ushort_t* pa2 = A + (size_t)ar2 * lda + sk;
  const ushort_t* pb1 = Bt + (size_t)(col0 + sr) * K + sk;
  const ushort_t* pb2 = Bt + (size_t)(col0 + 64 + sr) * K + sk;
  ushort_t* la1 = sA + 8 * t;
  ushort_t* la2 = sA + 8 * t + 2048;
  ushort_t* lb1 = sB + 8 * t;
  ushort_t* lb2 = sB + 8 * t + 2048;

  f32x4 acc[4][4] = {};

  const int nk = K >> 5;
  for (int kt = 0; kt < nk; ++kt) {
    const int k0 = kt << 5;
    gload16(la1, pa1 + k0);
    gload16(la2, pa2 + k0);
    gload16(lb1, pb1 + k0);
    gload16(lb2, pb2 + k0);
    __syncthreads();
    bf16x8 af[4], bfr[4];
#pragma unroll
    for (int m = 0; m < 4; ++m)
      af[m] = *(const bf16x8*)&sA[(wr + m * 16 + lr) * 32 + lk * 8];
#pragma unroll
    for (int n = 0; n < 4; ++n)
      bfr[n] = *(const bf16x8*)&sB[(wc + n * 16 + lr) * 32 + lk * 8];
#pragma unroll
    for (int m = 0; m < 4; ++m)
#pragma unroll
      for (int n = 0; n < 4; ++n)
        acc[m][n] = __builtin_amdgcn_mfma_f32_16x16x32_bf16(af[m], bfr[n], acc[m][n], 0, 0, 0);
    __syncthreads();
  }

#pragma unroll
  for (int n = 0; n < 4; ++n) {
    const int ocol = col0 + wc + n * 16 + lr;
    const float bv = bias[ocol];
#pragma unroll
    for (int m = 0; m < 4; ++m) {
      const int orow = row0 + wr + m * 16 + lk * 4;
      f32x4 v = acc[m][n];
#pragma unroll
      for (int r = 0; r < 4; ++r) {
        if (orow + r < M) {
          float o = v[r] + bv;
          if (RELU) o = fmaxf(o, 0.f);
          if (OUTBF)
            ((ushort_t*)Cout)[(size_t)(orow + r) * ldc + ocol] = f2bf(o);
          else
            ((float*)Cout)[(size_t)(orow + r) * ldc + ocol] = o;
        }
      }
    }
  }
}

extern "C" void kernel_launch(void* const* d_in, const int* in_sizes, int n_in,
                              void* d_out, int out_size, void* d_ws, size_t ws_size,
                              hipStream_t stream) {
  (void)n_in; (void)out_size; (void)ws_size;
  const float* x     = (const float*)d_in[0];
  const int*   eidx  = (const int*)d_in[1];
  const float* eattr = (const float*)d_in[2];
  const float* W1 = (const float*)d_in[6];
  const float* b1 = (const float*)d_in[7];
  const float* W3 = (const float*)d_in[8];
  const float* b3 = (const float*)d_in[9];
  const float* lng = (const float*)d_in[10];
  const float* lnb = (const float*)d_in[11];
  const float* W6 = (const float*)d_in[12];
  const float* b6 = (const float*)d_in[13];
  const float* W8 = (const float*)d_in[14];
  const float* b8 = (const float*)d_in[15];

  const int N = in_sizes[0] / 256;  // 20000
  const int E = in_sizes[2] / 256;  // 640000
  const int* col = eidx + E;        // edge_index[1]

  char* ws = (char*)d_ws;
  // h4 region [0, N*2048*4); seg+cnt alias its head (consumed before h4 is written)
  float* h4  = (float*)ws;
  float* seg = (float*)ws;
  float* cnt = (float*)(ws + (size_t)N * 256 * 4);
  size_t off = (size_t)N * 2048 * 4;
  ushort_t* hcat = (ushort_t*)(ws + off);  off += (size_t)N * 2560 * 2;  // [h5 | agg | x] bf16
  ushort_t* h2   = (ushort_t*)(ws + off);  off += (size_t)N * 2048 * 2;  // also reused as h7
  ushort_t* W1t = (ushort_t*)(ws + off);   off += (size_t)2048 * 512 * 2;
  ushort_t* W3t = (ushort_t*)(ws + off);   off += (size_t)2048 * 2048 * 2;
  ushort_t* W6t = (ushort_t*)(ws + off);   off += (size_t)2048 * 2560 * 2;
  ushort_t* W8t = (ushort_t*)(ws + off);   off += (size_t)512 * 2048 * 2;

  hipMemsetAsync(seg, 0, (size_t)N * 256 * 4 + (size_t)N * 4, stream);

  transpose_w<<<dim3(512 / 32, 2048 / 32), 256, 0, stream>>>(W1, W1t, 512, 2048);
  transpose_w<<<dim3(2048 / 32, 2048 / 32), 256, 0, stream>>>(W3, W3t, 2048, 2048);
  transpose_w<<<dim3(2560 / 32, 2048 / 32), 256, 0, stream>>>(W6, W6t, 2560, 2048);
  transpose_w<<<dim3(2048 / 32, 512 / 32), 256, 0, stream>>>(W8, W8t, 2048, 512);

  long nun = (long)E * 64;
  scatter_add_kernel<<<(int)((nun + 255) / 256), 256, 0, stream>>>(
      (const float4*)eattr, col, seg, cnt, E);

  build_h0<<<(N * 128 + 255) / 256, 256, 0, stream>>>(seg, cnt, x, hcat, N);

  const int Mt = (N + 127) / 128;
  // GEMM1: h0 [N,512] @ W1 -> h2 bf16 (ReLU)
  gemm_bt<1, 1><<<dim3(Mt, 16), 256, 0, stream>>>(hcat + 2048, 2560, W1t, b1, h2, 2048, N, 512);
  // GEMM2: h2 @ W3 -> h4 f32 (ReLU)
  gemm_bt<1, 0><<<dim3(Mt, 16), 256, 0, stream>>>(h2, 2048, W3t, b3, h4, 2048, N, 2048);
  // LN(h4) -> hcat[:, 0:2048] bf16
  ln_kernel<<<N, 256, 0, stream>>>(h4, lng, lnb, hcat);
  // GEMM3: hcat [N,2560] @ W6 -> h7 bf16 (ReLU), reuse h2 buffer
  gemm_bt<1, 1><<<dim3(Mt, 16), 256, 0, stream>>>(hcat, 2560, W6t, b6, h2, 2048, N, 2560);
  // GEMM4: h7 @ W8 -> out f32
  gemm_bt<0, 0><<<dim3(Mt, 4), 256, 0, stream>>>(h2, 2048, W8t, b8, (float*)d_out, 512, N, 2048);
}

// Round 2
// 1227.331 us; speedup vs baseline: 2.5966x; 2.5966x over previous
//
#include <hip/hip_runtime.h>

typedef unsigned short ushort_t;
typedef __attribute__((ext_vector_type(4))) float f32x4;
typedef __attribute__((ext_vector_type(8))) __bf16 bf16x8;
typedef __attribute__((ext_vector_type(8))) unsigned short u16x8;
typedef __attribute__((ext_vector_type(4))) unsigned short u16x4;

__device__ __forceinline__ unsigned short f2bf(float f) {
  union { float f; unsigned int u; } v; v.f = f;
  unsigned int u = v.u;
  u += 0x7fffu + ((u >> 16) & 1u);   // round-to-nearest-even
  return (unsigned short)(u >> 16);
}

__device__ __forceinline__ void gload16(ushort_t* lds, const ushort_t* g) {
  __builtin_amdgcn_global_load_lds(
      (const __attribute__((address_space(1))) unsigned int*)g,
      (__attribute__((address_space(3))) unsigned int*)lds, 16, 0, 0);
}

// ---------------- weight transpose + f32->bf16 convert:  in [R][C] f32 -> out [C][R] bf16
__global__ __launch_bounds__(256)
void transpose_w(const float* __restrict__ in, ushort_t* __restrict__ out, int R, int C) {
  __shared__ float tile[32][33];
  const int t = threadIdx.x;
  const int tx = t & 31, ty = t >> 5;
  const int r0 = blockIdx.x * 32, c0 = blockIdx.y * 32;
#pragma unroll
  for (int i = 0; i < 4; ++i)
    tile[ty + 8 * i][tx] = in[(size_t)(r0 + ty + 8 * i) * C + c0 + tx];
  __syncthreads();
#pragma unroll
  for (int i = 0; i < 4; ++i)
    out[(size_t)(c0 + ty + 8 * i) * R + r0 + tx] = f2bf(tile[tx][ty + 8 * i]);
}

// ---------------- CSR build: histogram, prefix scan, fill
__global__ __launch_bounds__(256)
void count_edges(const int* __restrict__ col, int* __restrict__ cnt, int E) {
  int i = blockIdx.x * 256 + threadIdx.x;
  if (i < E) atomicAdd(&cnt[col[i]], 1);
}

__global__ __launch_bounds__(1024)
void prefix_kernel(const int* __restrict__ cnt, int* __restrict__ start,
                   int* __restrict__ cursor, int N) {
  __shared__ int buf[1024];
  __shared__ int carry_s;
  if (threadIdx.x == 0) carry_s = 0;
  __syncthreads();
  for (int base = 0; base < N; base += 1024) {
    int i = base + threadIdx.x;
    int v = (i < N) ? cnt[i] : 0;
    buf[threadIdx.x] = v;
    __syncthreads();
    for (int off = 1; off < 1024; off <<= 1) {
      int tv = (threadIdx.x >= off) ? buf[threadIdx.x - off] : 0;
      __syncthreads();
      buf[threadIdx.x] += tv;
      __syncthreads();
    }
    int excl = carry_s + buf[threadIdx.x] - v;
    if (i < N) { start[i] = excl; cursor[i] = excl; }
    __syncthreads();
    if (threadIdx.x == 1023) carry_s += buf[1023];
    __syncthreads();
  }
}

__global__ __launch_bounds__(256)
void fill_csr(const int* __restrict__ col, int* __restrict__ cursor,
              int* __restrict__ eids, int E) {
  int i = blockIdx.x * 256 + threadIdx.x;
  if (i < E) {
    int p = atomicAdd(&cursor[col[i]], 1);
    eids[p] = i;
  }
}

// ---------------- gather-mean + build h0: one block per node, 256 threads = feature cols
__global__ __launch_bounds__(256)
void gather_mean(const float* __restrict__ eattr, const int* __restrict__ start,
                 const int* __restrict__ deg, const int* __restrict__ eids,
                 const float* __restrict__ x, ushort_t* __restrict__ hcat, int N) {
  const int row = blockIdx.x;
  const int t = threadIdx.x;
  const int s = start[row], d = deg[row];
  float sum = 0.f;
  int i = 0;
  for (; i + 4 <= d; i += 4) {
    int e0 = eids[s + i], e1 = eids[s + i + 1], e2 = eids[s + i + 2], e3 = eids[s + i + 3];
    float v0 = eattr[(size_t)e0 * 256 + t];
    float v1 = eattr[(size_t)e1 * 256 + t];
    float v2 = eattr[(size_t)e2 * 256 + t];
    float v3 = eattr[(size_t)e3 * 256 + t];
    sum += v0 + v1 + v2 + v3;
  }
  for (; i < d; ++i) sum += eattr[(size_t)eids[s + i] * 256 + t];
  const float mean = sum / fmaxf((float)d, 1.f);
  hcat[(size_t)row * 2560 + 2048 + t] = f2bf(mean);
  hcat[(size_t)row * 2560 + 2304 + t] = f2bf(x[(size_t)row * 256 + t]);
}

// ---------------- LayerNorm over h4 [N][2048] f32 -> bf16 into hcat[:, 0:2048]
__global__ __launch_bounds__(256)
void ln_kernel(const float* __restrict__ h4, const float* __restrict__ g,
               const float* __restrict__ b, ushort_t* __restrict__ hcat) {
  const int row = blockIdx.x;
  const int t = threadIdx.x;
  const float* p = h4 + (size_t)row * 2048;
  float4 v0 = *(const float4*)(p + t * 8);
  float4 v1 = *(const float4*)(p + t * 8 + 4);
  float vv[8] = {v0.x, v0.y, v0.z, v0.w, v1.x, v1.y, v1.z, v1.w};
  float s = 0.f, ss = 0.f;
#pragma unroll
  for (int j = 0; j < 8; ++j) { s += vv[j]; ss += vv[j] * vv[j]; }
#pragma unroll
  for (int o = 32; o > 0; o >>= 1) {
    s += __shfl_xor(s, o);
    ss += __shfl_xor(ss, o);
  }
  __shared__ float red[8];
  int w = t >> 6, l = t & 63;
  if (l == 0) { red[w] = s; red[4 + w] = ss; }
  __syncthreads();
  s = red[0] + red[1] + red[2] + red[3];
  ss = red[4] + red[5] + red[6] + red[7];
  const float mu = s * (1.f / 2048.f);
  const float var = ss * (1.f / 2048.f) - mu * mu;
  const float rs = rsqrtf(var + 1e-5f);
  float4 g0 = *(const float4*)(g + t * 8);
  float4 g1 = *(const float4*)(g + t * 8 + 4);
  float4 b0 = *(const float4*)(b + t * 8);
  float4 b1 = *(const float4*)(b + t * 8 + 4);
  float gg[8] = {g0.x, g0.y, g0.z, g0.w, g1.x, g1.y, g1.z, g1.w};
  float bb[8] = {b0.x, b0.y, b0.z, b0.w, b1.x, b1.y, b1.z, b1.w};
  u16x8 o8;
#pragma unroll
  for (int j = 0; j < 8; ++j) o8[j] = f2bf((vv[j] - mu) * rs * gg[j] + bb[j]);
  *(u16x8*)(hcat + (size_t)row * 2560 + t * 8) = o8;
}

// ---------------- bf16 MFMA GEMM: C[M][Nc] = A[M][K] @ Bt[Nc][K]^T + bias, m97 structure
// BM=BN=128, BK=32, 256 threads = 4 waves, each wave 64x64 (4x4 of 16x16x32)
template <int RELU, int OUTBF>
__global__ __launch_bounds__(256)
void gemm_bt(const ushort_t* __restrict__ A, int lda,
             const ushort_t* __restrict__ Bt,
             const float* __restrict__ bias,
             void* __restrict__ Cout, int ldc, int M, int K) {
  __shared__ __align__(16) ushort_t sA[128 * 32];
  __shared__ __align__(16) ushort_t sB[128 * 32];
  const int t = threadIdx.x;
  const int row0 = blockIdx.x * 128;
  const int col0 = blockIdx.y * 128;
  const int w = t >> 6, l = t & 63;
  const int wr = (w >> 1) * 64, wc = (w & 1) * 64;
  const int lr = l & 15, lk = l >> 4;

  const int sr = t >> 2;           // tile row 0..63
  const int sk = (t & 3) * 8;      // k offset
  int ar1 = row0 + sr;       if (ar1 > M - 1) ar1 = M - 1;
  int ar2 = row0 + 64 + sr;  if (ar2 > M - 1) ar2 = M - 1;
  const ushort_t* pa1 = A + (size_t)ar1 * lda + sk;
  const ushort_t* pa2 = A + (size_t)ar2 * lda + sk;
  const ushort_t* pb1 = Bt + (size_t)(col0 + sr) * K + sk;
  const ushort_t* pb2 = Bt + (size_t)(col0 + 64 + sr) * K + sk;
  ushort_t* la1 = sA + 8 * t;
  ushort_t* la2 = sA + 8 * t + 2048;
  ushort_t* lb1 = sB + 8 * t;
  ushort_t* lb2 = sB + 8 * t + 2048;

  f32x4 acc[4][4] = {};

  const int nk = K >> 5;
  for (int kt = 0; kt < nk; ++kt) {
    const int k0 = kt << 5;
    gload16(la1, pa1 + k0);
    gload16(la2, pa2 + k0);
    gload16(lb1, pb1 + k0);
    gload16(lb2, pb2 + k0);
    __syncthreads();
    bf16x8 af[4], bfr[4];
#pragma unroll
    for (int m = 0; m < 4; ++m)
      af[m] = *(const bf16x8*)&sA[(wr + m * 16 + lr) * 32 + lk * 8];
#pragma unroll
    for (int n = 0; n < 4; ++n)
      bfr[n] = *(const bf16x8*)&sB[(wc + n * 16 + lr) * 32 + lk * 8];
#pragma unroll
    for (int m = 0; m < 4; ++m)
#pragma unroll
      for (int n = 0; n < 4; ++n)
        acc[m][n] = __builtin_amdgcn_mfma_f32_16x16x32_bf16(af[m], bfr[n], acc[m][n], 0, 0, 0);
    __syncthreads();
  }

#pragma unroll
  for (int n = 0; n < 4; ++n) {
    const int ocol = col0 + wc + n * 16 + lr;
    const float bv = bias[ocol];
#pragma unroll
    for (int m = 0; m < 4; ++m) {
      const int orow = row0 + wr + m * 16 + lk * 4;
      f32x4 v = acc[m][n];
#pragma unroll
      for (int r = 0; r < 4; ++r) {
        if (orow + r < M) {
          float o = v[r] + bv;
          if (RELU) o = fmaxf(o, 0.f);
          if (OUTBF)
            ((ushort_t*)Cout)[(size_t)(orow + r) * ldc + ocol] = f2bf(o);
          else
            ((float*)Cout)[(size_t)(orow + r) * ldc + ocol] = o;
        }
      }
    }
  }
}

extern "C" void kernel_launch(void* const* d_in, const int* in_sizes, int n_in,
                              void* d_out, int out_size, void* d_ws, size_t ws_size,
                              hipStream_t stream) {
  (void)n_in; (void)out_size; (void)ws_size;
  const float* x     = (const float*)d_in[0];
  const int*   eidx  = (const int*)d_in[1];
  const float* eattr = (const float*)d_in[2];
  const float* W1 = (const float*)d_in[6];
  const float* b1 = (const float*)d_in[7];
  const float* W3 = (const float*)d_in[8];
  const float* b3 = (const float*)d_in[9];
  const float* lng = (const float*)d_in[10];
  const float* lnb = (const float*)d_in[11];
  const float* W6 = (const float*)d_in[12];
  const float* b6 = (const float*)d_in[13];
  const float* W8 = (const float*)d_in[14];
  const float* b8 = (const float*)d_in[15];

  const int N = in_sizes[0] / 256;  // 20000
  const int E = in_sizes[2] / 256;  // 640000
  const int* col = eidx + E;        // edge_index[1]

  char* ws = (char*)d_ws;
  float* h4  = (float*)ws;
  size_t off = (size_t)N * 2048 * 4;
  ushort_t* hcat = (ushort_t*)(ws + off);  off += (size_t)N * 2560 * 2;  // [h5 | agg | x] bf16
  ushort_t* h2   = (ushort_t*)(ws + off);  off += (size_t)N * 2048 * 2;  // also reused as h7
  ushort_t* W1t = (ushort_t*)(ws + off);   off += (size_t)2048 * 512 * 2;
  ushort_t* W3t = (ushort_t*)(ws + off);   off += (size_t)2048 * 2048 * 2;
  ushort_t* W6t = (ushort_t*)(ws + off);   off += (size_t)2048 * 2560 * 2;
  ushort_t* W8t = (ushort_t*)(ws + off);   off += (size_t)512 * 2048 * 2;
  int* deg    = (int*)(ws + off);  off += (size_t)N * 4;
  int* startp = (int*)(ws + off);  off += (size_t)N * 4;
  int* cursor = (int*)(ws + off);  off += (size_t)N * 4;
  int* eids   = (int*)(ws + off);  off += (size_t)E * 4;

  hipMemsetAsync(deg, 0, (size_t)N * 4, stream);

  transpose_w<<<dim3(512 / 32, 2048 / 32), 256, 0, stream>>>(W1, W1t, 512, 2048);
  transpose_w<<<dim3(2048 / 32, 2048 / 32), 256, 0, stream>>>(W3, W3t, 2048, 2048);
  transpose_w<<<dim3(2560 / 32, 2048 / 32), 256, 0, stream>>>(W6, W6t, 2560, 2048);
  transpose_w<<<dim3(2048 / 32, 512 / 32), 256, 0, stream>>>(W8, W8t, 2048, 512);

  // CSR build + gather-mean (replaces contended scatter atomics)
  count_edges<<<(E + 255) / 256, 256, 0, stream>>>(col, deg, E);
  prefix_kernel<<<1, 1024, 0, stream>>>(deg, startp, cursor, N);
  fill_csr<<<(E + 255) / 256, 256, 0, stream>>>(col, cursor, eids, E);
  gather_mean<<<N, 256, 0, stream>>>(eattr, startp, deg, eids, x, hcat, N);

  const int Mt = (N + 127) / 128;
  // GEMM1: h0 [N,512] @ W1 -> h2 bf16 (ReLU)
  gemm_bt<1, 1><<<dim3(Mt, 16), 256, 0, stream>>>(hcat + 2048, 2560, W1t, b1, h2, 2048, N, 512);
  // GEMM2: h2 @ W3 -> h4 f32 (ReLU)
  gemm_bt<1, 0><<<dim3(Mt, 16), 256, 0, stream>>>(h2, 2048, W3t, b3, h4, 2048, N, 2048);
  // LN(h4) -> hcat[:, 0:2048] bf16
  ln_kernel<<<N, 256, 0, stream>>>(h4, lng, lnb, hcat);
  // GEMM3: hcat [N,2560] @ W6 -> h7 bf16 (ReLU), reuse h2 buffer
  gemm_bt<1, 1><<<dim3(Mt, 16), 256, 0, stream>>>(hcat, 2560, W6t, b6, h2, 2048, N, 2560);
  // GEMM4: h7 @ W8 -> out f32
  gemm_bt<0, 0><<<dim3(Mt, 4), 256, 0, stream>>>(h2, 2048, W8t, b8, (float*)d_out, 512, N, 2048);
}

// Round 3
// 1122.100 us; speedup vs baseline: 2.8401x; 1.0938x over previous
//
#include <hip/hip_runtime.h>

typedef unsigned short ushort_t;
typedef __attribute__((ext_vector_type(4))) float f32x4;
typedef __attribute__((ext_vector_type(8))) __bf16 bf16x8;
typedef __attribute__((ext_vector_type(8))) unsigned short u16x8;
typedef __attribute__((ext_vector_type(4))) unsigned short u16x4;

__device__ __forceinline__ unsigned short f2bf(float f) {
  union { float f; unsigned int u; } v; v.f = f;
  unsigned int u = v.u;
  u += 0x7fffu + ((u >> 16) & 1u);   // round-to-nearest-even
  return (unsigned short)(u >> 16);
}

__device__ __forceinline__ void gload16(ushort_t* lds, const ushort_t* g) {
  __builtin_amdgcn_global_load_lds(
      (const __attribute__((address_space(1))) unsigned int*)g,
      (__attribute__((address_space(3))) unsigned int*)lds, 16, 0, 0);
}

// ---------------- weight transpose + f32->bf16 convert:  in [R][C] f32 -> out [C][R] bf16
__global__ __launch_bounds__(256)
void transpose_w(const float* __restrict__ in, ushort_t* __restrict__ out, int R, int C) {
  __shared__ float tile[32][33];
  const int t = threadIdx.x;
  const int tx = t & 31, ty = t >> 5;
  const int r0 = blockIdx.x * 32, c0 = blockIdx.y * 32;
#pragma unroll
  for (int i = 0; i < 4; ++i)
    tile[ty + 8 * i][tx] = in[(size_t)(r0 + ty + 8 * i) * C + c0 + tx];
  __syncthreads();
#pragma unroll
  for (int i = 0; i < 4; ++i)
    out[(size_t)(c0 + ty + 8 * i) * R + r0 + tx] = f2bf(tile[tx][ty + 8 * i]);
}

// ---------------- CSR build: histogram, prefix scan, fill
__global__ __launch_bounds__(256)
void count_edges(const int* __restrict__ col, int* __restrict__ cnt, int E) {
  int i = blockIdx.x * 256 + threadIdx.x;
  if (i < E) atomicAdd(&cnt[col[i]], 1);
}

__global__ __launch_bounds__(1024)
void prefix_kernel(const int* __restrict__ cnt, int* __restrict__ start,
                   int* __restrict__ cursor, int N) {
  __shared__ int buf[1024];
  __shared__ int carry_s;
  if (threadIdx.x == 0) carry_s = 0;
  __syncthreads();
  for (int base = 0; base < N; base += 1024) {
    int i = base + threadIdx.x;
    int v = (i < N) ? cnt[i] : 0;
    buf[threadIdx.x] = v;
    __syncthreads();
    for (int off = 1; off < 1024; off <<= 1) {
      int tv = (threadIdx.x >= off) ? buf[threadIdx.x - off] : 0;
      __syncthreads();
      buf[threadIdx.x] += tv;
      __syncthreads();
    }
    int excl = carry_s + buf[threadIdx.x] - v;
    if (i < N) { start[i] = excl; cursor[i] = excl; }
    __syncthreads();
    if (threadIdx.x == 1023) carry_s += buf[1023];
    __syncthreads();
  }
}

__global__ __launch_bounds__(256)
void fill_csr(const int* __restrict__ col, int* __restrict__ cursor,
              int* __restrict__ eids, int E) {
  int i = blockIdx.x * 256 + threadIdx.x;
  if (i < E) {
    int p = atomicAdd(&cursor[col[i]], 1);
    eids[p] = i;
  }
}

// ---------------- gather-mean + build h0: one block per node, 256 threads = feature cols
__global__ __launch_bounds__(256)
void gather_mean(const float* __restrict__ eattr, const int* __restrict__ start,
                 const int* __restrict__ deg, const int* __restrict__ eids,
                 const float* __restrict__ x, ushort_t* __restrict__ hcat, int N) {
  const int row = blockIdx.x;
  const int t = threadIdx.x;
  const int s = start[row], d = deg[row];
  float sum = 0.f;
  int i = 0;
  for (; i + 4 <= d; i += 4) {
    int e0 = eids[s + i], e1 = eids[s + i + 1], e2 = eids[s + i + 2], e3 = eids[s + i + 3];
    float v0 = eattr[(size_t)e0 * 256 + t];
    float v1 = eattr[(size_t)e1 * 256 + t];
    float v2 = eattr[(size_t)e2 * 256 + t];
    float v3 = eattr[(size_t)e3 * 256 + t];
    sum += v0 + v1 + v2 + v3;
  }
  for (; i < d; ++i) sum += eattr[(size_t)eids[s + i] * 256 + t];
  const float mean = sum / fmaxf((float)d, 1.f);
  hcat[(size_t)row * 2560 + 2048 + t] = f2bf(mean);
  hcat[(size_t)row * 2560 + 2304 + t] = f2bf(x[(size_t)row * 256 + t]);
}

// ---------------- LayerNorm over h4 [N][2048] f32 -> bf16 into hcat[:, 0:2048]
__global__ __launch_bounds__(256)
void ln_kernel(const float* __restrict__ h4, const float* __restrict__ g,
               const float* __restrict__ b, ushort_t* __restrict__ hcat) {
  const int row = blockIdx.x;
  const int t = threadIdx.x;
  const float* p = h4 + (size_t)row * 2048;
  float4 v0 = *(const float4*)(p + t * 8);
  float4 v1 = *(const float4*)(p + t * 8 + 4);
  float vv[8] = {v0.x, v0.y, v0.z, v0.w, v1.x, v1.y, v1.z, v1.w};
  float s = 0.f, ss = 0.f;
#pragma unroll
  for (int j = 0; j < 8; ++j) { s += vv[j]; ss += vv[j] * vv[j]; }
#pragma unroll
  for (int o = 32; o > 0; o >>= 1) {
    s += __shfl_xor(s, o);
    ss += __shfl_xor(ss, o);
  }
  __shared__ float red[8];
  int w = t >> 6, l = t & 63;
  if (l == 0) { red[w] = s; red[4 + w] = ss; }
  __syncthreads();
  s = red[0] + red[1] + red[2] + red[3];
  ss = red[4] + red[5] + red[6] + red[7];
  const float mu = s * (1.f / 2048.f);
  const float var = ss * (1.f / 2048.f) - mu * mu;
  const float rs = rsqrtf(var + 1e-5f);
  float4 g0 = *(const float4*)(g + t * 8);
  float4 g1 = *(const float4*)(g + t * 8 + 4);
  float4 b0 = *(const float4*)(b + t * 8);
  float4 b1 = *(const float4*)(b + t * 8 + 4);
  float gg[8] = {g0.x, g0.y, g0.z, g0.w, g1.x, g1.y, g1.z, g1.w};
  float bb[8] = {b0.x, b0.y, b0.z, b0.w, b1.x, b1.y, b1.z, b1.w};
  u16x8 o8;
#pragma unroll
  for (int j = 0; j < 8; ++j) o8[j] = f2bf((vv[j] - mu) * rs * gg[j] + bb[j]);
  *(u16x8*)(hcat + (size_t)row * 2560 + t * 8) = o8;
}

// ---------------- bf16 MFMA GEMM: C[M][Nc] = A[M][K] @ Bt[Nc][K]^T + bias, m97 structure
// BM=BN=128, BK=32, 256 threads = 4 waves, each wave 64x64 (4x4 of 16x16x32).
// Grid: dim3(n_col_tiles, n_row_tiles). Logical order: col-tile fastest (consecutive
// blocks share the A row-panel), plus bijective XCD chunk swizzle (T1/m204) so each
// XCD owns a contiguous band of row panels -> A streams from HBM exactly once.
template <int RELU, int OUTBF>
__global__ __launch_bounds__(256)
void gemm_bt(const ushort_t* __restrict__ A, int lda,
             const ushort_t* __restrict__ Bt,
             const float* __restrict__ bias,
             void* __restrict__ Cout, int ldc, int M, int K) {
  __shared__ __align__(16) ushort_t sA[128 * 32];
  __shared__ __align__(16) ushort_t sB[128 * 32];
  const int t = threadIdx.x;

  // ---- block index remap: XCD-contiguous chunks of a col-fastest tile order
  const int nct = gridDim.x;
  const int nwg = nct * gridDim.y;
  const int flat = blockIdx.y * nct + blockIdx.x;   // HW dispatch order
  const int xcd = flat & 7, loc = flat >> 3;
  const int q = nwg >> 3, r = nwg & 7;
  const int swz = (xcd < r ? xcd * (q + 1) : r * (q + 1) + (xcd - r) * q) + loc;
  const int row0 = (swz / nct) * 128;
  const int col0 = (swz % nct) * 128;

  const int w = t >> 6, l = t & 63;
  const int wr = (w >> 1) * 64, wc = (w & 1) * 64;
  const int lr = l & 15, lk = l >> 4;

  const int sr = t >> 2;           // tile row 0..63
  const int sk = (t & 3) * 8;      // k offset
  int ar1 = row0 + sr;       if (ar1 > M - 1) ar1 = M - 1;
  int ar2 = row0 + 64 + sr;  if (ar2 > M - 1) ar2 = M - 1;
  const ushort_t* pa1 = A + (size_t)ar1 * lda + sk;
  const ushort_t* pa2 = A + (size_t)ar2 * lda + sk;
  const ushort_t* pb1 = Bt + (size_t)(col0 + sr) * K + sk;
  const ushort_t* pb2 = Bt + (size_t)(col0 + 64 + sr) * K + sk;
  ushort_t* la1 = sA + 8 * t;
  ushort_t* la2 = sA + 8 * t + 2048;
  ushort_t* lb1 = sB + 8 * t;
  ushort_t* lb2 = sB + 8 * t + 2048;

  f32x4 acc[4][4] = {};

  const int nk = K >> 5;
  for (int kt = 0; kt < nk; ++kt) {
    const int k0 = kt << 5;
    gload16(la1, pa1 + k0);
    gload16(la2, pa2 + k0);
    gload16(lb1, pb1 + k0);
    gload16(lb2, pb2 + k0);
    __syncthreads();
    bf16x8 af[4], bfr[4];
#pragma unroll
    for (int m = 0; m < 4; ++m)
      af[m] = *(const bf16x8*)&sA[(wr + m * 16 + lr) * 32 + lk * 8];
#pragma unroll
    for (int n = 0; n < 4; ++n)
      bfr[n] = *(const bf16x8*)&sB[(wc + n * 16 + lr) * 32 + lk * 8];
#pragma unroll
    for (int m = 0; m < 4; ++m)
#pragma unroll
      for (int n = 0; n < 4; ++n)
        acc[m][n] = __builtin_amdgcn_mfma_f32_16x16x32_bf16(af[m], bfr[n], acc[m][n], 0, 0, 0);
    __syncthreads();
  }

#pragma unroll
  for (int n = 0; n < 4; ++n) {
    const int ocol = col0 + wc + n * 16 + lr;
    const float bv = bias[ocol];
#pragma unroll
    for (int m = 0; m < 4; ++m) {
      const int orow = row0 + wr + m * 16 + lk * 4;
      f32x4 v = acc[m][n];
#pragma unroll
      for (int r2 = 0; r2 < 4; ++r2) {
        if (orow + r2 < M) {
          float o = v[r2] + bv;
          if (RELU) o = fmaxf(o, 0.f);
          if (OUTBF)
            ((ushort_t*)Cout)[(size_t)(orow + r2) * ldc + ocol] = f2bf(o);
          else
            ((float*)Cout)[(size_t)(orow + r2) * ldc + ocol] = o;
        }
      }
    }
  }
}

extern "C" void kernel_launch(void* const* d_in, const int* in_sizes, int n_in,
                              void* d_out, int out_size, void* d_ws, size_t ws_size,
                              hipStream_t stream) {
  (void)n_in; (void)out_size; (void)ws_size;
  const float* x     = (const float*)d_in[0];
  const int*   eidx  = (const int*)d_in[1];
  const float* eattr = (const float*)d_in[2];
  const float* W1 = (const float*)d_in[6];
  const float* b1 = (const float*)d_in[7];
  const float* W3 = (const float*)d_in[8];
  const float* b3 = (const float*)d_in[9];
  const float* lng = (const float*)d_in[10];
  const float* lnb = (const float*)d_in[11];
  const float* W6 = (const float*)d_in[12];
  const float* b6 = (const float*)d_in[13];
  const float* W8 = (const float*)d_in[14];
  const float* b8 = (const float*)d_in[15];

  const int N = in_sizes[0] / 256;  // 20000
  const int E = in_sizes[2] / 256;  // 640000
  const int* col = eidx + E;        // edge_index[1]

  char* ws = (char*)d_ws;
  float* h4  = (float*)ws;
  size_t off = (size_t)N * 2048 * 4;
  ushort_t* hcat = (ushort_t*)(ws + off);  off += (size_t)N * 2560 * 2;  // [h5 | agg | x] bf16
  ushort_t* h2   = (ushort_t*)(ws + off);  off += (size_t)N * 2048 * 2;  // also reused as h7
  ushort_t* W1t = (ushort_t*)(ws + off);   off += (size_t)2048 * 512 * 2;
  ushort_t* W3t = (ushort_t*)(ws + off);   off += (size_t)2048 * 2048 * 2;
  ushort_t* W6t = (ushort_t*)(ws + off);   off += (size_t)2048 * 2560 * 2;
  ushort_t* W8t = (ushort_t*)(ws + off);   off += (size_t)512 * 2048 * 2;
  int* deg    = (int*)(ws + off);  off += (size_t)N * 4;
  int* startp = (int*)(ws + off);  off += (size_t)N * 4;
  int* cursor = (int*)(ws + off);  off += (size_t)N * 4;
  int* eids   = (int*)(ws + off);  off += (size_t)E * 4;

  hipMemsetAsync(deg, 0, (size_t)N * 4, stream);

  transpose_w<<<dim3(512 / 32, 2048 / 32), 256, 0, stream>>>(W1, W1t, 512, 2048);
  transpose_w<<<dim3(2048 / 32, 2048 / 32), 256, 0, stream>>>(W3, W3t, 2048, 2048);
  transpose_w<<<dim3(2560 / 32, 2048 / 32), 256, 0, stream>>>(W6, W6t, 2560, 2048);
  transpose_w<<<dim3(2048 / 32, 512 / 32), 256, 0, stream>>>(W8, W8t, 2048, 512);

  // CSR build + gather-mean (replaces contended scatter atomics)
  count_edges<<<(E + 255) / 256, 256, 0, stream>>>(col, deg, E);
  prefix_kernel<<<1, 1024, 0, stream>>>(deg, startp, cursor, N);
  fill_csr<<<(E + 255) / 256, 256, 0, stream>>>(col, cursor, eids, E);
  gather_mean<<<N, 256, 0, stream>>>(eattr, startp, deg, eids, x, hcat, N);

  const int Mt = (N + 127) / 128;
  // grids are dim3(n_col_tiles, n_row_tiles); kernel remaps to col-fastest + XCD chunks
  // GEMM1: h0 [N,512] @ W1 -> h2 bf16 (ReLU)
  gemm_bt<1, 1><<<dim3(16, Mt), 256, 0, stream>>>(hcat + 2048, 2560, W1t, b1, h2, 2048, N, 512);
  // GEMM2: h2 @ W3 -> h4 f32 (ReLU)
  gemm_bt<1, 0><<<dim3(16, Mt), 256, 0, stream>>>(h2, 2048, W3t, b3, h4, 2048, N, 2048);
  // LN(h4) -> hcat[:, 0:2048] bf16
  ln_kernel<<<N, 256, 0, stream>>>(h4, lng, lnb, hcat);
  // GEMM3: hcat [N,2560] @ W6 -> h7 bf16 (ReLU), reuse h2 buffer
  gemm_bt<1, 1><<<dim3(16, Mt), 256, 0, stream>>>(hcat, 2560, W6t, b6, h2, 2048, N, 2560);
  // GEMM4: h7 @ W8 -> out f32
  gemm_bt<0, 0><<<dim3(4, Mt), 256, 0, stream>>>(h2, 2048, W8t, b8, (float*)d_out, 512, N, 2048);
}

// Round 4
// 954.281 us; speedup vs baseline: 3.3396x; 1.1759x over previous
//
#include <hip/hip_runtime.h>

typedef unsigned short ushort_t;
typedef __attribute__((ext_vector_type(4))) float f32x4;
typedef __attribute__((ext_vector_type(8))) __bf16 bf16x8;
typedef __attribute__((ext_vector_type(8))) unsigned short u16x8;
typedef __attribute__((ext_vector_type(4))) unsigned short u16x4;

__device__ __forceinline__ unsigned short f2bf(float f) {
  union { float f; unsigned int u; } v; v.f = f;
  unsigned int u = v.u;
  u += 0x7fffu + ((u >> 16) & 1u);   // round-to-nearest-even
  return (unsigned short)(u >> 16);
}

__device__ __forceinline__ void gload16(ushort_t* lds, const ushort_t* g) {
  __builtin_amdgcn_global_load_lds(
      (const __attribute__((address_space(1))) unsigned int*)g,
      (__attribute__((address_space(3))) unsigned int*)lds, 16, 0, 0);
}

// ---------------- weight transpose + f32->bf16 convert:  in [R][C] f32 -> out [C][R] bf16
__global__ __launch_bounds__(256)
void transpose_w(const float* __restrict__ in, ushort_t* __restrict__ out, int R, int C) {
  __shared__ float tile[32][33];
  const int t = threadIdx.x;
  const int tx = t & 31, ty = t >> 5;
  const int r0 = blockIdx.x * 32, c0 = blockIdx.y * 32;
#pragma unroll
  for (int i = 0; i < 4; ++i)
    tile[ty + 8 * i][tx] = in[(size_t)(r0 + ty + 8 * i) * C + c0 + tx];
  __syncthreads();
#pragma unroll
  for (int i = 0; i < 4; ++i)
    out[(size_t)(c0 + ty + 8 * i) * R + r0 + tx] = f2bf(tile[tx][ty + 8 * i]);
}

// ---------------- CSR build: histogram, prefix scan, fill
__global__ __launch_bounds__(256)
void count_edges(const int* __restrict__ col, int* __restrict__ cnt, int E) {
  int i = blockIdx.x * 256 + threadIdx.x;
  if (i < E) atomicAdd(&cnt[col[i]], 1);
}

__global__ __launch_bounds__(1024)
void prefix_kernel(const int* __restrict__ cnt, int* __restrict__ start,
                   int* __restrict__ cursor, int N) {
  __shared__ int buf[1024];
  __shared__ int carry_s;
  if (threadIdx.x == 0) carry_s = 0;
  __syncthreads();
  for (int base = 0; base < N; base += 1024) {
    int i = base + threadIdx.x;
    int v = (i < N) ? cnt[i] : 0;
    buf[threadIdx.x] = v;
    __syncthreads();
    for (int off = 1; off < 1024; off <<= 1) {
      int tv = (threadIdx.x >= off) ? buf[threadIdx.x - off] : 0;
      __syncthreads();
      buf[threadIdx.x] += tv;
      __syncthreads();
    }
    int excl = carry_s + buf[threadIdx.x] - v;
    if (i < N) { start[i] = excl; cursor[i] = excl; }
    __syncthreads();
    if (threadIdx.x == 1023) carry_s += buf[1023];
    __syncthreads();
  }
}

__global__ __launch_bounds__(256)
void fill_csr(const int* __restrict__ col, int* __restrict__ cursor,
              int* __restrict__ eids, int E) {
  int i = blockIdx.x * 256 + threadIdx.x;
  if (i < E) {
    int p = atomicAdd(&cursor[col[i]], 1);
    eids[p] = i;
  }
}

// ---------------- gather-mean + build h0: one block per node, 256 threads = feature cols
__global__ __launch_bounds__(256)
void gather_mean(const float* __restrict__ eattr, const int* __restrict__ start,
                 const int* __restrict__ deg, const int* __restrict__ eids,
                 const float* __restrict__ x, ushort_t* __restrict__ hcat, int N) {
  const int row = blockIdx.x;
  const int t = threadIdx.x;
  const int s = start[row], d = deg[row];
  float sum = 0.f;
  int i = 0;
  for (; i + 4 <= d; i += 4) {
    int e0 = eids[s + i], e1 = eids[s + i + 1], e2 = eids[s + i + 2], e3 = eids[s + i + 3];
    float v0 = eattr[(size_t)e0 * 256 + t];
    float v1 = eattr[(size_t)e1 * 256 + t];
    float v2 = eattr[(size_t)e2 * 256 + t];
    float v3 = eattr[(size_t)e3 * 256 + t];
    sum += v0 + v1 + v2 + v3;
  }
  for (; i < d; ++i) sum += eattr[(size_t)eids[s + i] * 256 + t];
  const float mean = sum / fmaxf((float)d, 1.f);
  hcat[(size_t)row * 2560 + 2048 + t] = f2bf(mean);
  hcat[(size_t)row * 2560 + 2304 + t] = f2bf(x[(size_t)row * 256 + t]);
}

// ---------------- LayerNorm over h4 [N][2048] f32 -> bf16 into hcat[:, 0:2048]
__global__ __launch_bounds__(256)
void ln_kernel(const float* __restrict__ h4, const float* __restrict__ g,
               const float* __restrict__ b, ushort_t* __restrict__ hcat) {
  const int row = blockIdx.x;
  const int t = threadIdx.x;
  const float* p = h4 + (size_t)row * 2048;
  float4 v0 = *(const float4*)(p + t * 8);
  float4 v1 = *(const float4*)(p + t * 8 + 4);
  float vv[8] = {v0.x, v0.y, v0.z, v0.w, v1.x, v1.y, v1.z, v1.w};
  float s = 0.f, ss = 0.f;
#pragma unroll
  for (int j = 0; j < 8; ++j) { s += vv[j]; ss += vv[j] * vv[j]; }
#pragma unroll
  for (int o = 32; o > 0; o >>= 1) {
    s += __shfl_xor(s, o);
    ss += __shfl_xor(ss, o);
  }
  __shared__ float red[8];
  int w = t >> 6, l = t & 63;
  if (l == 0) { red[w] = s; red[4 + w] = ss; }
  __syncthreads();
  s = red[0] + red[1] + red[2] + red[3];
  ss = red[4] + red[5] + red[6] + red[7];
  const float mu = s * (1.f / 2048.f);
  const float var = ss * (1.f / 2048.f) - mu * mu;
  const float rs = rsqrtf(var + 1e-5f);
  float4 g0 = *(const float4*)(g + t * 8);
  float4 g1 = *(const float4*)(g + t * 8 + 4);
  float4 b0 = *(const float4*)(b + t * 8);
  float4 b1 = *(const float4*)(b + t * 8 + 4);
  float gg[8] = {g0.x, g0.y, g0.z, g0.w, g1.x, g1.y, g1.z, g1.w};
  float bb[8] = {b0.x, b0.y, b0.z, b0.w, b1.x, b1.y, b1.z, b1.w};
  u16x8 o8;
#pragma unroll
  for (int j = 0; j < 8; ++j) o8[j] = f2bf((vv[j] - mu) * rs * gg[j] + bb[j]);
  *(u16x8*)(hcat + (size_t)row * 2560 + t * 8) = o8;
}

// ======================= 256x256 8-wave deep-pipelined GEMM =======================
// BM=BN=256, BK=64, 512 threads = 8 waves (2M x 4N), per-wave C = 128x64.
// LDS: 2 bufs x (A 256x64 | B 256x64) bf16 = 128 KiB. XOR-swizzle: 16B slot ^= row&7,
// applied via pre-swizzled GLOBAL source (linear global_load_lds dest) + swizzled ds_read.
// Pipeline (per K-tile k, 4 phases): ph0 stages (k+1).A1, ph1 (k+1).B1,
// ph2 (k+2).B0, ph3 (k+2).A0 + s_waitcnt vmcnt(4). Ledger: at k.ph3 drain,
// outstanding = 12 loads, oldest 8 = K-tile k+1 complete; every stage targets a
// region whose K-tile-k reads finished behind an earlier barrier.

__device__ __forceinline__ void read_a4(bf16x8 (&dst)[4][2], const char* sb, int bufoff,
                                        int aoff, int slot0, int slot1, int g) {
#pragma unroll
  for (int m = 0; m < 4; ++m) {
    const char* p = sb + bufoff + aoff + (g * 4 + m) * 2048;
    dst[m][0] = *(const bf16x8*)(p + slot0);
    dst[m][1] = *(const bf16x8*)(p + slot1);
  }
}

__device__ __forceinline__ void read_b2(bf16x8 (&dst)[2][2], const char* sb, int bufoff,
                                        int boff, int slot0, int slot1, int g) {
#pragma unroll
  for (int n = 0; n < 2; ++n) {
    const char* p = sb + bufoff + boff + (g * 2 + n) * 2048;
    dst[n][0] = *(const bf16x8*)(p + slot0);
    dst[n][1] = *(const bf16x8*)(p + slot1);
  }
}

__device__ __forceinline__ void mfma_q(f32x4 (&acc)[8][4], const bf16x8 (&a)[4][2],
                                       const bf16x8 (&b)[2][2], int mg, int ng) {
#pragma unroll
  for (int m = 0; m < 4; ++m)
#pragma unroll
    for (int n = 0; n < 2; ++n)
#pragma unroll
      for (int kk = 0; kk < 2; ++kk)
        acc[mg * 4 + m][ng * 2 + n] = __builtin_amdgcn_mfma_f32_16x16x32_bf16(
            a[m][kk], b[n][kk], acc[mg * 4 + m][ng * 2 + n], 0, 0, 0);
}

#define SBAR() do { __builtin_amdgcn_sched_barrier(0); \
                    __builtin_amdgcn_s_barrier(); \
                    __builtin_amdgcn_sched_barrier(0); } while (0)

template <int RELU, int OUTBF>
__global__ __launch_bounds__(512, 2)
void gemm256(const ushort_t* __restrict__ A, int lda,
             const ushort_t* __restrict__ Bt,
             const float* __restrict__ bias,
             void* __restrict__ Cout, int ldc, int M, int K) {
  __shared__ __align__(16) ushort_t smem[65536];  // 128 KiB
  char* sb = (char*)smem;
  const int t = threadIdx.x;

  // block remap: col-fastest + bijective XCD chunks
  const int nct = gridDim.x;
  const int nwg = nct * gridDim.y;
  const int flat = blockIdx.y * nct + blockIdx.x;
  const int xcd = flat & 7, loc = flat >> 3;
  const int q = nwg >> 3, r = nwg & 7;
  const int swz = (xcd < r ? xcd * (q + 1) : r * (q + 1) + (xcd - r) * q) + loc;
  const int row0 = (swz / nct) * 256;
  const int col0 = (swz % nct) * 256;

  const int wid = t >> 6, l = t & 63;
  const int wr = wid >> 2, wc = wid & 3;   // 2 x 4 waves
  const int lr = l & 15, lk = l >> 4;

  // ---- staging source pointers (pre-swizzled column)
  const int srow = t >> 3;                                  // 0..63 per load
  const int scol = ((t & 7) ^ ((t >> 3) & 7)) << 3;         // swizzled col (elems)
  const ushort_t* pa[2][2];
  const ushort_t* pb[2][2];
#pragma unroll
  for (int h = 0; h < 2; ++h)
#pragma unroll
    for (int L = 0; L < 2; ++L) {
      int ra = row0 + h * 128 + L * 64 + srow;
      if (ra > M - 1) ra = M - 1;
      pa[h][L] = A + (size_t)ra * lda + scol;
      pb[h][L] = Bt + (size_t)(col0 + h * 128 + L * 64 + srow) * K + scol;
    }
  const int tb = t * 16;  // LDS byte offset of this thread's 16B within a load region

  // ---- reader byte offsets (swizzled)
  const int slot0 = ((lk ^ (lr & 7)) << 4);
  const int slot1 = (((4 + lk) ^ (lr & 7)) << 4);
  const int aoff = (wr * 128 + lr) * 128;
  const int boff = 32768 + (wc * 64 + lr) * 128;

  f32x4 acc[8][4] = {};
  bf16x8 af[4][2], af2[4][2], bf[2][2], bf2[2][2];

  const int nk = K >> 6;

  // ---- prologue: stage tile0 {A0,A1,B0,B1}, tile1 {B0,A0}; drain to tile0
  {
    gload16((ushort_t*)(sb + 0 + tb), pa[0][0]);
    gload16((ushort_t*)(sb + 8192 + tb), pa[0][1]);
    gload16((ushort_t*)(sb + 16384 + tb), pa[1][0]);
    gload16((ushort_t*)(sb + 24576 + tb), pa[1][1]);
    gload16((ushort_t*)(sb + 32768 + tb), pb[0][0]);
    gload16((ushort_t*)(sb + 40960 + tb), pb[0][1]);
    gload16((ushort_t*)(sb + 49152 + tb), pb[1][0]);
    gload16((ushort_t*)(sb + 57344 + tb), pb[1][1]);
    const int k1 = (nk > 1) ? 1 : 0;
    gload16((ushort_t*)(sb + 65536 + 32768 + tb), pb[0][0] + (k1 << 6));
    gload16((ushort_t*)(sb + 65536 + 40960 + tb), pb[0][1] + (k1 << 6));
    gload16((ushort_t*)(sb + 65536 + 0 + tb), pa[0][0] + (k1 << 6));
    gload16((ushort_t*)(sb + 65536 + 8192 + tb), pa[0][1] + (k1 << 6));
  }
  asm volatile("s_waitcnt vmcnt(4)" ::: "memory");
  SBAR();

  for (int k = 0; k < nk; ++k) {
    const int cur = (k & 1) << 16, nxt = cur ^ 65536;
    const int kc1 = ((k + 1 < nk) ? k + 1 : nk - 1) << 6;
    const int kc2 = ((k + 2 < nk) ? k + 2 : nk - 1) << 6;

    // ---- ph0: read A(mi0-3), B(nj0-1); stage (k+1).A1 -> nxt; MFMA q(0,0)
    read_a4(af, sb, cur, aoff, slot0, slot1, 0);
    read_b2(bf, sb, cur, boff, slot0, slot1, 0);
    gload16((ushort_t*)(sb + nxt + 16384 + tb), pa[1][0] + kc1);
    gload16((ushort_t*)(sb + nxt + 24576 + tb), pa[1][1] + kc1);
    SBAR();
    __builtin_amdgcn_s_setprio(1);
    mfma_q(acc, af, bf, 0, 0);
    __builtin_amdgcn_s_setprio(0);
    SBAR();

    // ---- ph1: read B(nj2-3); stage (k+1).B1 -> nxt; MFMA q(0,1)
    read_b2(bf2, sb, cur, boff, slot0, slot1, 1);
    gload16((ushort_t*)(sb + nxt + 49152 + tb), pb[1][0] + kc1);
    gload16((ushort_t*)(sb + nxt + 57344 + tb), pb[1][1] + kc1);
    SBAR();
    __builtin_amdgcn_s_setprio(1);
    mfma_q(acc, af, bf2, 0, 1);
    __builtin_amdgcn_s_setprio(0);
    SBAR();

    // ---- ph2: read A(mi4-7); stage (k+2).B0 -> cur (B reads done @ph1); MFMA q(1,0)
    read_a4(af2, sb, cur, aoff, slot0, slot1, 1);
    gload16((ushort_t*)(sb + cur + 32768 + tb), pb[0][0] + kc2);
    gload16((ushort_t*)(sb + cur + 40960 + tb), pb[0][1] + kc2);
    SBAR();
    __builtin_amdgcn_s_setprio(1);
    mfma_q(acc, af2, bf, 1, 0);
    __builtin_amdgcn_s_setprio(0);
    SBAR();

    // ---- ph3: stage (k+2).A0 -> cur (A reads done @ph2); drain; MFMA q(1,1)
    gload16((ushort_t*)(sb + cur + 0 + tb), pa[0][0] + kc2);
    gload16((ushort_t*)(sb + cur + 8192 + tb), pa[0][1] + kc2);
    asm volatile("s_waitcnt vmcnt(4)" ::: "memory");
    SBAR();
    __builtin_amdgcn_s_setprio(1);
    mfma_q(acc, af2, bf2, 1, 1);
    __builtin_amdgcn_s_setprio(0);
    SBAR();
  }

  // ---- epilogue: bias + optional ReLU + store
#pragma unroll
  for (int nj = 0; nj < 4; ++nj) {
    const int ocol = col0 + wc * 64 + nj * 16 + lr;
    const float bv = bias[ocol];
#pragma unroll
    for (int mi = 0; mi < 8; ++mi) {
      const int orow = row0 + wr * 128 + mi * 16 + lk * 4;
      f32x4 v = acc[mi][nj];
#pragma unroll
      for (int r2 = 0; r2 < 4; ++r2) {
        if (orow + r2 < M) {
          float o = v[r2] + bv;
          if (RELU) o = fmaxf(o, 0.f);
          if (OUTBF)
            ((ushort_t*)Cout)[(size_t)(orow + r2) * ldc + ocol] = f2bf(o);
          else
            ((float*)Cout)[(size_t)(orow + r2) * ldc + ocol] = o;
        }
      }
    }
  }
}

// ---------------- 128x128 2-phase GEMM (kept for GEMM4: N=512)
template <int RELU, int OUTBF>
__global__ __launch_bounds__(256)
void gemm_bt(const ushort_t* __restrict__ A, int lda,
             const ushort_t* __restrict__ Bt,
             const float* __restrict__ bias,
             void* __restrict__ Cout, int ldc, int M, int K) {
  __shared__ __align__(16) ushort_t sA[128 * 32];
  __shared__ __align__(16) ushort_t sB[128 * 32];
  const int t = threadIdx.x;

  const int nct = gridDim.x;
  const int nwg = nct * gridDim.y;
  const int flat = blockIdx.y * nct + blockIdx.x;
  const int xcd = flat & 7, loc = flat >> 3;
  const int q = nwg >> 3, r = nwg & 7;
  const int swz = (xcd < r ? xcd * (q + 1) : r * (q + 1) + (xcd - r) * q) + loc;
  const int row0 = (swz / nct) * 128;
  const int col0 = (swz % nct) * 128;

  const int w = t >> 6, l = t & 63;
  const int wr = (w >> 1) * 64, wc = (w & 1) * 64;
  const int lr = l & 15, lk = l >> 4;

  const int sr = t >> 2;
  const int sk = (t & 3) * 8;
  int ar1 = row0 + sr;       if (ar1 > M - 1) ar1 = M - 1;
  int ar2 = row0 + 64 + sr;  if (ar2 > M - 1) ar2 = M - 1;
  const ushort_t* pa1 = A + (size_t)ar1 * lda + sk;
  const ushort_t* pa2 = A + (size_t)ar2 * lda + sk;
  const ushort_t* pb1 = Bt + (size_t)(col0 + sr) * K + sk;
  const ushort_t* pb2 = Bt + (size_t)(col0 + 64 + sr) * K + sk;
  ushort_t* la1 = sA + 8 * t;
  ushort_t* la2 = sA + 8 * t + 2048;
  ushort_t* lb1 = sB + 8 * t;
  ushort_t* lb2 = sB + 8 * t + 2048;

  f32x4 acc[4][4] = {};

  const int nk = K >> 5;
  for (int kt = 0; kt < nk; ++kt) {
    const int k0 = kt << 5;
    gload16(la1, pa1 + k0);
    gload16(la2, pa2 + k0);
    gload16(lb1, pb1 + k0);
    gload16(lb2, pb2 + k0);
    __syncthreads();
    bf16x8 af[4], bfr[4];
#pragma unroll
    for (int m = 0; m < 4; ++m)
      af[m] = *(const bf16x8*)&sA[(wr + m * 16 + lr) * 32 + lk * 8];
#pragma unroll
    for (int n = 0; n < 4; ++n)
      bfr[n] = *(const bf16x8*)&sB[(wc + n * 16 + lr) * 32 + lk * 8];
#pragma unroll
    for (int m = 0; m < 4; ++m)
#pragma unroll
      for (int n = 0; n < 4; ++n)
        acc[m][n] = __builtin_amdgcn_mfma_f32_16x16x32_bf16(af[m], bfr[n], acc[m][n], 0, 0, 0);
    __syncthreads();
  }

#pragma unroll
  for (int n = 0; n < 4; ++n) {
    const int ocol = col0 + wc + n * 16 + lr;
    const float bv = bias[ocol];
#pragma unroll
    for (int m = 0; m < 4; ++m) {
      const int orow = row0 + wr + m * 16 + lk * 4;
      f32x4 v = acc[m][n];
#pragma unroll
      for (int r2 = 0; r2 < 4; ++r2) {
        if (orow + r2 < M) {
          float o = v[r2] + bv;
          if (RELU) o = fmaxf(o, 0.f);
          if (OUTBF)
            ((ushort_t*)Cout)[(size_t)(orow + r2) * ldc + ocol] = f2bf(o);
          else
            ((float*)Cout)[(size_t)(orow + r2) * ldc + ocol] = o;
        }
      }
    }
  }
}

extern "C" void kernel_launch(void* const* d_in, const int* in_sizes, int n_in,
                              void* d_out, int out_size, void* d_ws, size_t ws_size,
                              hipStream_t stream) {
  (void)n_in; (void)out_size; (void)ws_size;
  const float* x     = (const float*)d_in[0];
  const int*   eidx  = (const int*)d_in[1];
  const float* eattr = (const float*)d_in[2];
  const float* W1 = (const float*)d_in[6];
  const float* b1 = (const float*)d_in[7];
  const float* W3 = (const float*)d_in[8];
  const float* b3 = (const float*)d_in[9];
  const float* lng = (const float*)d_in[10];
  const float* lnb = (const float*)d_in[11];
  const float* W6 = (const float*)d_in[12];
  const float* b6 = (const float*)d_in[13];
  const float* W8 = (const float*)d_in[14];
  const float* b8 = (const float*)d_in[15];

  const int N = in_sizes[0] / 256;  // 20000
  const int E = in_sizes[2] / 256;  // 640000
  const int* col = eidx + E;        // edge_index[1]

  char* ws = (char*)d_ws;
  float* h4  = (float*)ws;
  size_t off = (size_t)N * 2048 * 4;
  ushort_t* hcat = (ushort_t*)(ws + off);  off += (size_t)N * 2560 * 2;  // [h5 | agg | x] bf16
  ushort_t* h2   = (ushort_t*)(ws + off);  off += (size_t)N * 2048 * 2;  // also reused as h7
  ushort_t* W1t = (ushort_t*)(ws + off);   off += (size_t)2048 * 512 * 2;
  ushort_t* W3t = (ushort_t*)(ws + off);   off += (size_t)2048 * 2048 * 2;
  ushort_t* W6t = (ushort_t*)(ws + off);   off += (size_t)2048 * 2560 * 2;
  ushort_t* W8t = (ushort_t*)(ws + off);   off += (size_t)512 * 2048 * 2;
  int* deg    = (int*)(ws + off);  off += (size_t)N * 4;
  int* startp = (int*)(ws + off);  off += (size_t)N * 4;
  int* cursor = (int*)(ws + off);  off += (size_t)N * 4;
  int* eids   = (int*)(ws + off);  off += (size_t)E * 4;

  hipMemsetAsync(deg, 0, (size_t)N * 4, stream);

  transpose_w<<<dim3(512 / 32, 2048 / 32), 256, 0, stream>>>(W1, W1t, 512, 2048);
  transpose_w<<<dim3(2048 / 32, 2048 / 32), 256, 0, stream>>>(W3, W3t, 2048, 2048);
  transpose_w<<<dim3(2560 / 32, 2048 / 32), 256, 0, stream>>>(W6, W6t, 2560, 2048);
  transpose_w<<<dim3(2048 / 32, 512 / 32), 256, 0, stream>>>(W8, W8t, 2048, 512);

  // CSR build + gather-mean
  count_edges<<<(E + 255) / 256, 256, 0, stream>>>(col, deg, E);
  prefix_kernel<<<1, 1024, 0, stream>>>(deg, startp, cursor, N);
  fill_csr<<<(E + 255) / 256, 256, 0, stream>>>(col, cursor, eids, E);
  gather_mean<<<N, 256, 0, stream>>>(eattr, startp, deg, eids, x, hcat, N);

  const int Mt256 = (N + 255) / 256;   // 79
  const int Mt128 = (N + 127) / 128;   // 157
  // GEMM1: h0 [N,512] @ W1 -> h2 bf16 (ReLU)
  gemm256<1, 1><<<dim3(8, Mt256), 512, 0, stream>>>(hcat + 2048, 2560, W1t, b1, h2, 2048, N, 512);
  // GEMM2: h2 @ W3 -> h4 f32 (ReLU)
  gemm256<1, 0><<<dim3(8, Mt256), 512, 0, stream>>>(h2, 2048, W3t, b3, h4, 2048, N, 2048);
  // LN(h4) -> hcat[:, 0:2048] bf16
  ln_kernel<<<N, 256, 0, stream>>>(h4, lng, lnb, hcat);
  // GEMM3: hcat [N,2560] @ W6 -> h7 bf16 (ReLU), reuse h2 buffer
  gemm256<1, 1><<<dim3(8, Mt256), 512, 0, stream>>>(hcat, 2560, W6t, b6, h2, 2048, N, 2560);
  // GEMM4: h7 @ W8 -> out f32 (128^2 kernel: N=512 -> only 2 col tiles of 256)
  gemm_bt<0, 0><<<dim3(4, Mt128), 256, 0, stream>>>(h2, 2048, W8t, b8, (float*)d_out, 512, N, 2048);
}

// Round 5
// 932.650 us; speedup vs baseline: 3.4170x; 1.0232x over previous
//
#include <hip/hip_runtime.h>

typedef unsigned short ushort_t;
typedef __attribute__((ext_vector_type(4))) float f32x4;
typedef __attribute__((ext_vector_type(8))) __bf16 bf16x8;
typedef __attribute__((ext_vector_type(8))) unsigned short u16x8;
typedef __attribute__((ext_vector_type(4))) unsigned short u16x4;

__device__ __forceinline__ unsigned short f2bf(float f) {
  union { float f; unsigned int u; } v; v.f = f;
  unsigned int u = v.u;
  u += 0x7fffu + ((u >> 16) & 1u);   // round-to-nearest-even
  return (unsigned short)(u >> 16);
}

__device__ __forceinline__ float bf2f(unsigned short h) {
  union { unsigned int u; float f; } v; v.u = ((unsigned int)h) << 16;
  return v.f;
}

__device__ __forceinline__ void gload16(ushort_t* lds, const ushort_t* g) {
  __builtin_amdgcn_global_load_lds(
      (const __attribute__((address_space(1))) unsigned int*)g,
      (__attribute__((address_space(3))) unsigned int*)lds, 16, 0, 0);
}

// ---------------- weight transpose + f32->bf16 convert:  in [R][C] f32 -> out [C][R] bf16
__global__ __launch_bounds__(256)
void transpose_w(const float* __restrict__ in, ushort_t* __restrict__ out, int R, int C) {
  __shared__ float tile[32][33];
  const int t = threadIdx.x;
  const int tx = t & 31, ty = t >> 5;
  const int r0 = blockIdx.x * 32, c0 = blockIdx.y * 32;
#pragma unroll
  for (int i = 0; i < 4; ++i)
    tile[ty + 8 * i][tx] = in[(size_t)(r0 + ty + 8 * i) * C + c0 + tx];
  __syncthreads();
#pragma unroll
  for (int i = 0; i < 4; ++i)
    out[(size_t)(c0 + ty + 8 * i) * R + r0 + tx] = f2bf(tile[tx][ty + 8 * i]);
}

// ---------------- CSR build: histogram, prefix scan, fill
__global__ __launch_bounds__(256)
void count_edges(const int* __restrict__ col, int* __restrict__ cnt, int E) {
  int i = blockIdx.x * 256 + threadIdx.x;
  if (i < E) atomicAdd(&cnt[col[i]], 1);
}

// per-thread chunk + wave shfl-scan; 2 barriers total (was ~420)
__global__ __launch_bounds__(1024)
void prefix_kernel(const int* __restrict__ cnt, int* __restrict__ start,
                   int* __restrict__ cursor, int N) {
  const int t = threadIdx.x;
  const int chunk = (N + 1023) >> 10;
  const int base = t * chunk;
  int s = 0;
  for (int j = 0; j < chunk; ++j) {
    int i = base + j;
    s += (i < N) ? cnt[i] : 0;
  }
  const int lane = t & 63, wv = t >> 6;
  int scan = s;
#pragma unroll
  for (int o = 1; o < 64; o <<= 1) {
    int up = __shfl_up(scan, o);
    if (lane >= o) scan += up;
  }
  __shared__ int wsum[16];
  if (lane == 63) wsum[wv] = scan;
  __syncthreads();
  if (t == 0) {
    int acc = 0;
#pragma unroll
    for (int i2 = 0; i2 < 16; ++i2) { int v = wsum[i2]; wsum[i2] = acc; acc += v; }
  }
  __syncthreads();
  int run = wsum[wv] + (scan - s);   // exclusive offset for this thread's chunk
  for (int j = 0; j < chunk; ++j) {
    int i = base + j;
    if (i < N) {
      start[i] = run; cursor[i] = run;
      run += cnt[i];
    }
  }
}

__global__ __launch_bounds__(256)
void fill_csr(const int* __restrict__ col, int* __restrict__ cursor,
              int* __restrict__ eids, int E) {
  int i = blockIdx.x * 256 + threadIdx.x;
  if (i < E) {
    int p = atomicAdd(&cursor[col[i]], 1);
    eids[p] = i;
  }
}

// ---------------- gather-mean + build h0: block/node, wave-per-edge, float4/lane
__global__ __launch_bounds__(256)
void gather_mean(const float* __restrict__ eattr, const int* __restrict__ start,
                 const int* __restrict__ deg, const int* __restrict__ eids,
                 const float* __restrict__ x, ushort_t* __restrict__ hcat, int N) {
  const int row = blockIdx.x;
  const int t = threadIdx.x;
  const int w = t >> 6, l = t & 63;
  const int s = start[row], d = deg[row];
  const float4* ea4 = (const float4*)eattr;
  float4 sum = make_float4(0.f, 0.f, 0.f, 0.f);
  for (int i = w; i < d; i += 4) {
    int e = eids[s + i];
    float4 v = ea4[(size_t)e * 64 + l];
    sum.x += v.x; sum.y += v.y; sum.z += v.z; sum.w += v.w;
  }
  __shared__ float4 part[4][64];
  part[w][l] = sum;
  __syncthreads();
  // x -> hcat[:, 2304:2560] (all 256 threads)
  hcat[(size_t)row * 2560 + 2304 + t] = f2bf(x[(size_t)row * 256 + t]);
  if (w == 0) {
    float4 a = part[0][l], b = part[1][l], c = part[2][l], dd = part[3][l];
    const float inv = 1.f / fmaxf((float)d, 1.f);
    u16x4 o;
    o[0] = f2bf((a.x + b.x + c.x + dd.x) * inv);
    o[1] = f2bf((a.y + b.y + c.y + dd.y) * inv);
    o[2] = f2bf((a.z + b.z + c.z + dd.z) * inv);
    o[3] = f2bf((a.w + b.w + c.w + dd.w) * inv);
    *(u16x4*)(hcat + (size_t)row * 2560 + 2048 + l * 4) = o;
  }
}

// ---------------- LayerNorm IN PLACE over hcat[:, 0:2048] bf16 (row-local)
__global__ __launch_bounds__(256)
void ln_kernel(ushort_t* __restrict__ hcat, const float* __restrict__ g,
               const float* __restrict__ b) {
  const int row = blockIdx.x;
  const int t = threadIdx.x;
  ushort_t* p = hcat + (size_t)row * 2560 + t * 8;
  u16x8 raw = *(const u16x8*)p;
  float vv[8];
#pragma unroll
  for (int j = 0; j < 8; ++j) vv[j] = bf2f(raw[j]);
  float s = 0.f, ss = 0.f;
#pragma unroll
  for (int j = 0; j < 8; ++j) { s += vv[j]; ss += vv[j] * vv[j]; }
#pragma unroll
  for (int o = 32; o > 0; o >>= 1) {
    s += __shfl_xor(s, o);
    ss += __shfl_xor(ss, o);
  }
  __shared__ float red[8];
  int w = t >> 6, l = t & 63;
  if (l == 0) { red[w] = s; red[4 + w] = ss; }
  __syncthreads();
  s = red[0] + red[1] + red[2] + red[3];
  ss = red[4] + red[5] + red[6] + red[7];
  const float mu = s * (1.f / 2048.f);
  const float var = ss * (1.f / 2048.f) - mu * mu;
  const float rs = rsqrtf(var + 1e-5f);
  float4 g0 = *(const float4*)(g + t * 8);
  float4 g1 = *(const float4*)(g + t * 8 + 4);
  float4 b0 = *(const float4*)(b + t * 8);
  float4 b1 = *(const float4*)(b + t * 8 + 4);
  float gg[8] = {g0.x, g0.y, g0.z, g0.w, g1.x, g1.y, g1.z, g1.w};
  float bb[8] = {b0.x, b0.y, b0.z, b0.w, b1.x, b1.y, b1.z, b1.w};
  u16x8 o8;
#pragma unroll
  for (int j = 0; j < 8; ++j) o8[j] = f2bf((vv[j] - mu) * rs * gg[j] + bb[j]);
  *(u16x8*)p = o8;
}

// ======================= 256x256 8-wave deep-pipelined GEMM =======================
// BM=BN=256, BK=64, 512 threads = 8 waves (2M x 4N), per-wave C = 128x64.
// LDS: 2 bufs x (A 256x64 | B 256x64) bf16 = 128 KiB. XOR-swizzle via pre-swizzled
// global source (linear global_load_lds dest) + swizzled ds_read. 4 phases/K-tile,
// counted vmcnt(4) once per K-tile (ledger verified: drain leaves next tile complete).

__device__ __forceinline__ void read_a4(bf16x8 (&dst)[4][2], const char* sb, int bufoff,
                                        int aoff, int slot0, int slot1, int g) {
#pragma unroll
  for (int m = 0; m < 4; ++m) {
    const char* p = sb + bufoff + aoff + (g * 4 + m) * 2048;
    dst[m][0] = *(const bf16x8*)(p + slot0);
    dst[m][1] = *(const bf16x8*)(p + slot1);
  }
}

__device__ __forceinline__ void read_b2(bf16x8 (&dst)[2][2], const char* sb, int bufoff,
                                        int boff, int slot0, int slot1, int g) {
#pragma unroll
  for (int n = 0; n < 2; ++n) {
    const char* p = sb + bufoff + boff + (g * 2 + n) * 2048;
    dst[n][0] = *(const bf16x8*)(p + slot0);
    dst[n][1] = *(const bf16x8*)(p + slot1);
  }
}

__device__ __forceinline__ void mfma_q(f32x4 (&acc)[8][4], const bf16x8 (&a)[4][2],
                                       const bf16x8 (&b)[2][2], int mg, int ng) {
#pragma unroll
  for (int m = 0; m < 4; ++m)
#pragma unroll
    for (int n = 0; n < 2; ++n)
#pragma unroll
      for (int kk = 0; kk < 2; ++kk)
        acc[mg * 4 + m][ng * 2 + n] = __builtin_amdgcn_mfma_f32_16x16x32_bf16(
            a[m][kk], b[n][kk], acc[mg * 4 + m][ng * 2 + n], 0, 0, 0);
}

#define SBAR() do { __builtin_amdgcn_sched_barrier(0); \
                    __builtin_amdgcn_s_barrier(); \
                    __builtin_amdgcn_sched_barrier(0); } while (0)

template <int RELU, int OUTBF>
__global__ __launch_bounds__(512, 2)
void gemm256(const ushort_t* __restrict__ A, int lda,
             const ushort_t* __restrict__ Bt,
             const float* __restrict__ bias,
             void* __restrict__ Cout, int ldc, int M, int K) {
  __shared__ __align__(16) ushort_t smem[65536];  // 128 KiB
  char* sb = (char*)smem;
  const int t = threadIdx.x;

  // block remap: col-fastest + bijective XCD chunks
  const int nct = gridDim.x;
  const int nwg = nct * gridDim.y;
  const int flat = blockIdx.y * nct + blockIdx.x;
  const int xcd = flat & 7, loc = flat >> 3;
  const int q = nwg >> 3, r = nwg & 7;
  const int swz = (xcd < r ? xcd * (q + 1) : r * (q + 1) + (xcd - r) * q) + loc;
  const int row0 = (swz / nct) * 256;
  const int col0 = (swz % nct) * 256;

  const int wid = t >> 6, l = t & 63;
  const int wr = wid >> 2, wc = wid & 3;   // 2 x 4 waves
  const int lr = l & 15, lk = l >> 4;

  // ---- staging source pointers (pre-swizzled column)
  const int srow = t >> 3;
  const int scol = ((t & 7) ^ ((t >> 3) & 7)) << 3;
  const ushort_t* pa[2][2];
  const ushort_t* pb[2][2];
#pragma unroll
  for (int h = 0; h < 2; ++h)
#pragma unroll
    for (int L = 0; L < 2; ++L) {
      int ra = row0 + h * 128 + L * 64 + srow;
      if (ra > M - 1) ra = M - 1;
      pa[h][L] = A + (size_t)ra * lda + scol;
      pb[h][L] = Bt + (size_t)(col0 + h * 128 + L * 64 + srow) * K + scol;
    }
  const int tb = t * 16;

  const int slot0 = ((lk ^ (lr & 7)) << 4);
  const int slot1 = (((4 + lk) ^ (lr & 7)) << 4);
  const int aoff = (wr * 128 + lr) * 128;
  const int boff = 32768 + (wc * 64 + lr) * 128;

  f32x4 acc[8][4] = {};
  bf16x8 af[4][2], af2[4][2], bf[2][2], bf2[2][2];

  const int nk = K >> 6;

  {
    gload16((ushort_t*)(sb + 0 + tb), pa[0][0]);
    gload16((ushort_t*)(sb + 8192 + tb), pa[0][1]);
    gload16((ushort_t*)(sb + 16384 + tb), pa[1][0]);
    gload16((ushort_t*)(sb + 24576 + tb), pa[1][1]);
    gload16((ushort_t*)(sb + 32768 + tb), pb[0][0]);
    gload16((ushort_t*)(sb + 40960 + tb), pb[0][1]);
    gload16((ushort_t*)(sb + 49152 + tb), pb[1][0]);
    gload16((ushort_t*)(sb + 57344 + tb), pb[1][1]);
    const int k1 = (nk > 1) ? 1 : 0;
    gload16((ushort_t*)(sb + 65536 + 32768 + tb), pb[0][0] + (k1 << 6));
    gload16((ushort_t*)(sb + 65536 + 40960 + tb), pb[0][1] + (k1 << 6));
    gload16((ushort_t*)(sb + 65536 + 0 + tb), pa[0][0] + (k1 << 6));
    gload16((ushort_t*)(sb + 65536 + 8192 + tb), pa[0][1] + (k1 << 6));
  }
  asm volatile("s_waitcnt vmcnt(4)" ::: "memory");
  SBAR();

  for (int k = 0; k < nk; ++k) {
    const int cur = (k & 1) << 16, nxt = cur ^ 65536;
    const int kc1 = ((k + 1 < nk) ? k + 1 : nk - 1) << 6;
    const int kc2 = ((k + 2 < nk) ? k + 2 : nk - 1) << 6;

    read_a4(af, sb, cur, aoff, slot0, slot1, 0);
    read_b2(bf, sb, cur, boff, slot0, slot1, 0);
    gload16((ushort_t*)(sb + nxt + 16384 + tb), pa[1][0] + kc1);
    gload16((ushort_t*)(sb + nxt + 24576 + tb), pa[1][1] + kc1);
    SBAR();
    __builtin_amdgcn_s_setprio(1);
    mfma_q(acc, af, bf, 0, 0);
    __builtin_amdgcn_s_setprio(0);
    SBAR();

    read_b2(bf2, sb, cur, boff, slot0, slot1, 1);
    gload16((ushort_t*)(sb + nxt + 49152 + tb), pb[1][0] + kc1);
    gload16((ushort_t*)(sb + nxt + 57344 + tb), pb[1][1] + kc1);
    SBAR();
    __builtin_amdgcn_s_setprio(1);
    mfma_q(acc, af, bf2, 0, 1);
    __builtin_amdgcn_s_setprio(0);
    SBAR();

    read_a4(af2, sb, cur, aoff, slot0, slot1, 1);
    gload16((ushort_t*)(sb + cur + 32768 + tb), pb[0][0] + kc2);
    gload16((ushort_t*)(sb + cur + 40960 + tb), pb[0][1] + kc2);
    SBAR();
    __builtin_amdgcn_s_setprio(1);
    mfma_q(acc, af2, bf, 1, 0);
    __builtin_amdgcn_s_setprio(0);
    SBAR();

    gload16((ushort_t*)(sb + cur + 0 + tb), pa[0][0] + kc2);
    gload16((ushort_t*)(sb + cur + 8192 + tb), pa[0][1] + kc2);
    asm volatile("s_waitcnt vmcnt(4)" ::: "memory");
    SBAR();
    __builtin_amdgcn_s_setprio(1);
    mfma_q(acc, af2, bf2, 1, 1);
    __builtin_amdgcn_s_setprio(0);
    SBAR();
  }

#pragma unroll
  for (int nj = 0; nj < 4; ++nj) {
    const int ocol = col0 + wc * 64 + nj * 16 + lr;
    const float bv = bias[ocol];
#pragma unroll
    for (int mi = 0; mi < 8; ++mi) {
      const int orow = row0 + wr * 128 + mi * 16 + lk * 4;
      f32x4 v = acc[mi][nj];
#pragma unroll
      for (int r2 = 0; r2 < 4; ++r2) {
        if (orow + r2 < M) {
          float o = v[r2] + bv;
          if (RELU) o = fmaxf(o, 0.f);
          if (OUTBF)
            ((ushort_t*)Cout)[(size_t)(orow + r2) * ldc + ocol] = f2bf(o);
          else
            ((float*)Cout)[(size_t)(orow + r2) * ldc + ocol] = o;
        }
      }
    }
  }
}

extern "C" void kernel_launch(void* const* d_in, const int* in_sizes, int n_in,
                              void* d_out, int out_size, void* d_ws, size_t ws_size,
                              hipStream_t stream) {
  (void)n_in; (void)out_size; (void)ws_size;
  const float* x     = (const float*)d_in[0];
  const int*   eidx  = (const int*)d_in[1];
  const float* eattr = (const float*)d_in[2];
  const float* W1 = (const float*)d_in[6];
  const float* b1 = (const float*)d_in[7];
  const float* W3 = (const float*)d_in[8];
  const float* b3 = (const float*)d_in[9];
  const float* lng = (const float*)d_in[10];
  const float* lnb = (const float*)d_in[11];
  const float* W6 = (const float*)d_in[12];
  const float* b6 = (const float*)d_in[13];
  const float* W8 = (const float*)d_in[14];
  const float* b8 = (const float*)d_in[15];

  const int N = in_sizes[0] / 256;  // 20000
  const int E = in_sizes[2] / 256;  // 640000
  const int* col = eidx + E;        // edge_index[1]

  char* ws = (char*)d_ws;
  size_t off = 0;
  ushort_t* hcat = (ushort_t*)(ws + off);  off += (size_t)N * 2560 * 2;  // [h5/h4 | agg | x] bf16
  ushort_t* h2   = (ushort_t*)(ws + off);  off += (size_t)N * 2048 * 2;  // also reused as h7
  ushort_t* W1t = (ushort_t*)(ws + off);   off += (size_t)2048 * 512 * 2;
  ushort_t* W3t = (ushort_t*)(ws + off);   off += (size_t)2048 * 2048 * 2;
  ushort_t* W6t = (ushort_t*)(ws + off);   off += (size_t)2048 * 2560 * 2;
  ushort_t* W8t = (ushort_t*)(ws + off);   off += (size_t)512 * 2048 * 2;
  int* deg    = (int*)(ws + off);  off += (size_t)N * 4;
  int* startp = (int*)(ws + off);  off += (size_t)N * 4;
  int* cursor = (int*)(ws + off);  off += (size_t)N * 4;
  int* eids   = (int*)(ws + off);  off += (size_t)E * 4;

  hipMemsetAsync(deg, 0, (size_t)N * 4, stream);

  transpose_w<<<dim3(512 / 32, 2048 / 32), 256, 0, stream>>>(W1, W1t, 512, 2048);
  transpose_w<<<dim3(2048 / 32, 2048 / 32), 256, 0, stream>>>(W3, W3t, 2048, 2048);
  transpose_w<<<dim3(2560 / 32, 2048 / 32), 256, 0, stream>>>(W6, W6t, 2560, 2048);
  transpose_w<<<dim3(2048 / 32, 512 / 32), 256, 0, stream>>>(W8, W8t, 2048, 512);

  // CSR build + gather-mean
  count_edges<<<(E + 255) / 256, 256, 0, stream>>>(col, deg, E);
  prefix_kernel<<<1, 1024, 0, stream>>>(deg, startp, cursor, N);
  fill_csr<<<(E + 255) / 256, 256, 0, stream>>>(col, cursor, eids, E);
  gather_mean<<<N, 256, 0, stream>>>(eattr, startp, deg, eids, x, hcat, N);

  const int Mt256 = (N + 255) / 256;   // 79
  // GEMM1: h0 [N,512] @ W1 -> h2 bf16 (ReLU)
  gemm256<1, 1><<<dim3(8, Mt256), 512, 0, stream>>>(hcat + 2048, 2560, W1t, b1, h2, 2048, N, 512);
  // GEMM2: h2 @ W3 -> h4 bf16 (ReLU) DIRECTLY into hcat[:, 0:2048]
  gemm256<1, 1><<<dim3(8, Mt256), 512, 0, stream>>>(h2, 2048, W3t, b3, hcat, 2560, N, 2048);
  // LN in place on hcat[:, 0:2048]
  ln_kernel<<<N, 256, 0, stream>>>(hcat, lng, lnb);
  // GEMM3: hcat [N,2560] @ W6 -> h7 bf16 (ReLU), reuse h2 buffer
  gemm256<1, 1><<<dim3(8, Mt256), 512, 0, stream>>>(hcat, 2560, W6t, b6, h2, 2048, N, 2560);
  // GEMM4: h7 @ W8 -> out f32 (256^2 kernel, 2 col-tiles)
  gemm256<0, 0><<<dim3(2, Mt256), 512, 0, stream>>>(h2, 2048, W8t, b8, (float*)d_out, 512, N, 2048);
}

// Round 6
// 882.391 us; speedup vs baseline: 3.6117x; 1.0570x over previous
//
#include <hip/hip_runtime.h>

typedef unsigned short ushort_t;
typedef __attribute__((ext_vector_type(4))) float f32x4;
typedef __attribute__((ext_vector_type(8))) __bf16 bf16x8;
typedef __attribute__((ext_vector_type(8))) unsigned short u16x8;
typedef __attribute__((ext_vector_type(4))) unsigned short u16x4;

__device__ __forceinline__ unsigned short f2bf(float f) {
  union { float f; unsigned int u; } v; v.f = f;
  unsigned int u = v.u;
  u += 0x7fffu + ((u >> 16) & 1u);   // round-to-nearest-even
  return (unsigned short)(u >> 16);
}

__device__ __forceinline__ float bf2f(unsigned short h) {
  union { unsigned int u; float f; } v; v.u = ((unsigned int)h) << 16;
  return v.f;
}

__device__ __forceinline__ void gload16(ushort_t* lds, const ushort_t* g) {
  __builtin_amdgcn_global_load_lds(
      (const __attribute__((address_space(1))) unsigned int*)g,
      (__attribute__((address_space(3))) unsigned int*)lds, 16, 0, 0);
}

// ---------------- weight transpose + f32->bf16 convert:  in [R][C] f32 -> out [C][R] bf16
__global__ __launch_bounds__(256)
void transpose_w(const float* __restrict__ in, ushort_t* __restrict__ out, int R, int C) {
  __shared__ float tile[32][33];
  const int t = threadIdx.x;
  const int tx = t & 31, ty = t >> 5;
  const int r0 = blockIdx.x * 32, c0 = blockIdx.y * 32;
#pragma unroll
  for (int i = 0; i < 4; ++i)
    tile[ty + 8 * i][tx] = in[(size_t)(r0 + ty + 8 * i) * C + c0 + tx];
  __syncthreads();
#pragma unroll
  for (int i = 0; i < 4; ++i)
    out[(size_t)(c0 + ty + 8 * i) * R + r0 + tx] = f2bf(tile[tx][ty + 8 * i]);
}

// ---------------- CSR build: histogram, prefix scan, fill
__global__ __launch_bounds__(256)
void count_edges(const int* __restrict__ col, int* __restrict__ cnt, int E) {
  int i = blockIdx.x * 256 + threadIdx.x;
  if (i < E) atomicAdd(&cnt[col[i]], 1);
}

__global__ __launch_bounds__(1024)
void prefix_kernel(const int* __restrict__ cnt, int* __restrict__ start,
                   int* __restrict__ cursor, int N) {
  const int t = threadIdx.x;
  const int chunk = (N + 1023) >> 10;
  const int base = t * chunk;
  int s = 0;
  for (int j = 0; j < chunk; ++j) {
    int i = base + j;
    s += (i < N) ? cnt[i] : 0;
  }
  const int lane = t & 63, wv = t >> 6;
  int scan = s;
#pragma unroll
  for (int o = 1; o < 64; o <<= 1) {
    int up = __shfl_up(scan, o);
    if (lane >= o) scan += up;
  }
  __shared__ int wsum[16];
  if (lane == 63) wsum[wv] = scan;
  __syncthreads();
  if (t == 0) {
    int acc = 0;
#pragma unroll
    for (int i2 = 0; i2 < 16; ++i2) { int v = wsum[i2]; wsum[i2] = acc; acc += v; }
  }
  __syncthreads();
  int run = wsum[wv] + (scan - s);
  for (int j = 0; j < chunk; ++j) {
    int i = base + j;
    if (i < N) {
      start[i] = run; cursor[i] = run;
      run += cnt[i];
    }
  }
}

__global__ __launch_bounds__(256)
void fill_csr(const int* __restrict__ col, int* __restrict__ cursor,
              int* __restrict__ eids, int E) {
  int i = blockIdx.x * 256 + threadIdx.x;
  if (i < E) {
    int p = atomicAdd(&cursor[col[i]], 1);
    eids[p] = i;
  }
}

// ---------------- gather-mean + build h0: block/node, wave-per-edge, float4/lane
__global__ __launch_bounds__(256)
void gather_mean(const float* __restrict__ eattr, const int* __restrict__ start,
                 const int* __restrict__ deg, const int* __restrict__ eids,
                 const float* __restrict__ x, ushort_t* __restrict__ hcat, int N) {
  const int row = blockIdx.x;
  const int t = threadIdx.x;
  const int w = t >> 6, l = t & 63;
  const int s = start[row], d = deg[row];
  const float4* ea4 = (const float4*)eattr;
  float4 sum = make_float4(0.f, 0.f, 0.f, 0.f);
  for (int i = w; i < d; i += 4) {
    int e = eids[s + i];
    float4 v = ea4[(size_t)e * 64 + l];
    sum.x += v.x; sum.y += v.y; sum.z += v.z; sum.w += v.w;
  }
  __shared__ float4 part[4][64];
  part[w][l] = sum;
  __syncthreads();
  hcat[(size_t)row * 2560 + 2304 + t] = f2bf(x[(size_t)row * 256 + t]);
  if (w == 0) {
    float4 a = part[0][l], b = part[1][l], c = part[2][l], dd = part[3][l];
    const float inv = 1.f / fmaxf((float)d, 1.f);
    u16x4 o;
    o[0] = f2bf((a.x + b.x + c.x + dd.x) * inv);
    o[1] = f2bf((a.y + b.y + c.y + dd.y) * inv);
    o[2] = f2bf((a.z + b.z + c.z + dd.z) * inv);
    o[3] = f2bf((a.w + b.w + c.w + dd.w) * inv);
    *(u16x4*)(hcat + (size_t)row * 2560 + 2048 + l * 4) = o;
  }
}

// ---------------- LayerNorm IN PLACE over hcat[:, 0:2048] bf16 (row-local)
__global__ __launch_bounds__(256)
void ln_kernel(ushort_t* __restrict__ hcat, const float* __restrict__ g,
               const float* __restrict__ b) {
  const int row = blockIdx.x;
  const int t = threadIdx.x;
  ushort_t* p = hcat + (size_t)row * 2560 + t * 8;
  u16x8 raw = *(const u16x8*)p;
  float vv[8];
#pragma unroll
  for (int j = 0; j < 8; ++j) vv[j] = bf2f(raw[j]);
  float s = 0.f, ss = 0.f;
#pragma unroll
  for (int j = 0; j < 8; ++j) { s += vv[j]; ss += vv[j] * vv[j]; }
#pragma unroll
  for (int o = 32; o > 0; o >>= 1) {
    s += __shfl_xor(s, o);
    ss += __shfl_xor(ss, o);
  }
  __shared__ float red[8];
  int w = t >> 6, l = t & 63;
  if (l == 0) { red[w] = s; red[4 + w] = ss; }
  __syncthreads();
  s = red[0] + red[1] + red[2] + red[3];
  ss = red[4] + red[5] + red[6] + red[7];
  const float mu = s * (1.f / 2048.f);
  const float var = ss * (1.f / 2048.f) - mu * mu;
  const float rs = rsqrtf(var + 1e-5f);
  float4 g0 = *(const float4*)(g + t * 8);
  float4 g1 = *(const float4*)(g + t * 8 + 4);
  float4 b0 = *(const float4*)(b + t * 8);
  float4 b1 = *(const float4*)(b + t * 8 + 4);
  float gg[8] = {g0.x, g0.y, g0.z, g0.w, g1.x, g1.y, g1.z, g1.w};
  float bb[8] = {b0.x, b0.y, b0.z, b0.w, b1.x, b1.y, b1.z, b1.w};
  u16x8 o8;
#pragma unroll
  for (int j = 0; j < 8; ++j) o8[j] = f2bf((vv[j] - mu) * rs * gg[j] + bb[j]);
  *(u16x8*)p = o8;
}

// ======================= 128x256 8-wave GEMM, BK=32, 2 blocks/CU =======================
// 512 threads = 8 waves (2M x 4N), per-wave C = 64x64 (acc[4][4] = 64 VGPR).
// LDS: 3 bufs x (A 128x32 | B 256x32) bf16 = 72 KiB -> with ~116 VGPR and
// __launch_bounds__(512,4): 2 blocks/CU (cross-block overlap hides barriers/drains).
// Swizzle: 64B rows, 16B slot ^= row&3 (2-way bank alias = free), applied via
// pre-swizzled global source (linear gload_lds dest) + XOR'd ds_read.
// Depth-2 prefetch ledger (FIFO, per K-tile): ph0 stages (k+2).B0,B1 into
// buf[(k+2)%3]; ph1 stages (k+2).A; drain vmcnt(3) at end of ph1 completes
// exactly tile k+1, leaves k+2's 3 loads in flight. Prologue: 6 issues, vmcnt(3).
// Stage targets hold tile k-1 data, fully read 1-2 barriers earlier -> no races.

#define SBAR() do { __builtin_amdgcn_sched_barrier(0); \
                    __builtin_amdgcn_s_barrier(); \
                    __builtin_amdgcn_sched_barrier(0); } while (0)

template <int RELU, int OUTBF>
__global__ __launch_bounds__(512, 4)
void gemm128(const ushort_t* __restrict__ A, int lda,
             const ushort_t* __restrict__ Bt,
             const float* __restrict__ bias,
             void* __restrict__ Cout, int ldc, int M, int K) {
  __shared__ __align__(16) ushort_t smem[36864];  // 72 KiB = 3 x 24 KiB
  char* sb = (char*)smem;
  const int t = threadIdx.x;

  // block remap: col-fastest + bijective XCD chunks
  const int nct = gridDim.x;
  const int nwg = nct * gridDim.y;
  const int flat = blockIdx.y * nct + blockIdx.x;
  const int xcd = flat & 7, loc = flat >> 3;
  const int q = nwg >> 3, r = nwg & 7;
  const int swz = (xcd < r ? xcd * (q + 1) : r * (q + 1) + (xcd - r) * q) + loc;
  const int row0 = (swz / nct) * 128;
  const int col0 = (swz % nct) * 256;

  const int wid = t >> 6, l = t & 63;
  const int wr = wid >> 2, wc = wid & 3;   // 2 x 4 waves, per-wave 64x64
  const int lr = l & 15, lk = l >> 4;

  // ---- staging: thread t -> row t>>2 (0..127), 16B slot t&3; source col pre-swizzled
  const int srow = t >> 2;
  const int scol = ((t & 3) ^ ((t >> 2) & 3)) << 3;   // elems
  int ar = row0 + srow; if (ar > M - 1) ar = M - 1;
  const ushort_t* pa  = A + (size_t)ar * lda + scol;
  const ushort_t* pb0 = Bt + (size_t)(col0 + srow) * K + scol;
  const ushort_t* pb1 = pb0 + (size_t)128 * K;
  const int tb = t * 16;

  // ---- reader offsets: row pitch 64B, slot xor (row&3) == (lr&3)
  const int sx = ((lk ^ (lr & 3)) << 4);
  const int arow = (wr * 64 + lr) * 64 + sx;            // + m*1024
  const int brow = 8192 + (wc * 64 + lr) * 64 + sx;     // + n*1024

  f32x4 acc[4][4] = {};
  bf16x8 a[4], b01[2], b23[2];

  const int nk = K >> 5;

  // ---- prologue: tile0 {B0,B1,A}, tile1 {B0,B1,A}; drain to tile0 (vmcnt(3))
  {
    const int k1 = (nk > 1) ? 32 : 0;
    gload16((ushort_t*)(sb + 8192 + tb), pb0);
    gload16((ushort_t*)(sb + 16384 + tb), pb1);
    gload16((ushort_t*)(sb + 0 + tb), pa);
    gload16((ushort_t*)(sb + 24576 + 8192 + tb), pb0 + k1);
    gload16((ushort_t*)(sb + 24576 + 16384 + tb), pb1 + k1);
    gload16((ushort_t*)(sb + 24576 + 0 + tb), pa + k1);
  }
  asm volatile("s_waitcnt vmcnt(3)" ::: "memory");
  SBAR();

  int cO = 0, sO = 49152;  // current buf, stage buf = (k+2)%3
  for (int k = 0; k < nk; ++k) {
    const int kc2 = ((k + 2 < nk) ? k + 2 : nk - 1) << 5;  // elem offset

    // ---- ph0: read a0-3, b0-1 from cur; stage (k+2).B0,B1; MFMA n=0,1
#pragma unroll
    for (int m = 0; m < 4; ++m)
      a[m] = *(const bf16x8*)(sb + cO + arow + m * 1024);
#pragma unroll
    for (int n = 0; n < 2; ++n)
      b01[n] = *(const bf16x8*)(sb + cO + brow + n * 1024);
    gload16((ushort_t*)(sb + sO + 8192 + tb), pb0 + kc2);
    gload16((ushort_t*)(sb + sO + 16384 + tb), pb1 + kc2);
    SBAR();
    __builtin_amdgcn_s_setprio(1);
#pragma unroll
    for (int m = 0; m < 4; ++m)
#pragma unroll
      for (int n = 0; n < 2; ++n)
        acc[m][n] = __builtin_amdgcn_mfma_f32_16x16x32_bf16(a[m], b01[n], acc[m][n], 0, 0, 0);
    __builtin_amdgcn_s_setprio(0);
    SBAR();

    // ---- ph1: read b2-3; stage (k+2).A; MFMA n=2,3; drain vmcnt(3)
#pragma unroll
    for (int n = 0; n < 2; ++n)
      b23[n] = *(const bf16x8*)(sb + cO + brow + (2 + n) * 1024);
    gload16((ushort_t*)(sb + sO + 0 + tb), pa + kc2);
    SBAR();
    __builtin_amdgcn_s_setprio(1);
#pragma unroll
    for (int m = 0; m < 4; ++m)
#pragma unroll
      for (int n = 0; n < 2; ++n)
        acc[m][2 + n] = __builtin_amdgcn_mfma_f32_16x16x32_bf16(a[m], b23[n], acc[m][2 + n], 0, 0, 0);
    __builtin_amdgcn_s_setprio(0);
    asm volatile("s_waitcnt vmcnt(3)" ::: "memory");
    SBAR();

    cO = (cO == 49152) ? 0 : cO + 24576;
    sO = (sO == 49152) ? 0 : sO + 24576;
  }

  // ---- epilogue: bias + optional ReLU + store
#pragma unroll
  for (int nj = 0; nj < 4; ++nj) {
    const int ocol = col0 + wc * 64 + nj * 16 + lr;
    const float bv = bias[ocol];
#pragma unroll
    for (int mi = 0; mi < 4; ++mi) {
      const int orow = row0 + wr * 64 + mi * 16 + lk * 4;
      f32x4 v = acc[mi][nj];
#pragma unroll
      for (int r2 = 0; r2 < 4; ++r2) {
        if (orow + r2 < M) {
          float o = v[r2] + bv;
          if (RELU) o = fmaxf(o, 0.f);
          if (OUTBF)
            ((ushort_t*)Cout)[(size_t)(orow + r2) * ldc + ocol] = f2bf(o);
          else
            ((float*)Cout)[(size_t)(orow + r2) * ldc + ocol] = o;
        }
      }
    }
  }
}

extern "C" void kernel_launch(void* const* d_in, const int* in_sizes, int n_in,
                              void* d_out, int out_size, void* d_ws, size_t ws_size,
                              hipStream_t stream) {
  (void)n_in; (void)out_size; (void)ws_size;
  const float* x     = (const float*)d_in[0];
  const int*   eidx  = (const int*)d_in[1];
  const float* eattr = (const float*)d_in[2];
  const float* W1 = (const float*)d_in[6];
  const float* b1 = (const float*)d_in[7];
  const float* W3 = (const float*)d_in[8];
  const float* b3 = (const float*)d_in[9];
  const float* lng = (const float*)d_in[10];
  const float* lnb = (const float*)d_in[11];
  const float* W6 = (const float*)d_in[12];
  const float* b6 = (const float*)d_in[13];
  const float* W8 = (const float*)d_in[14];
  const float* b8 = (const float*)d_in[15];

  const int N = in_sizes[0] / 256;  // 20000
  const int E = in_sizes[2] / 256;  // 640000
  const int* col = eidx + E;        // edge_index[1]

  char* ws = (char*)d_ws;
  size_t off = 0;
  ushort_t* hcat = (ushort_t*)(ws + off);  off += (size_t)N * 2560 * 2;  // [h5/h4 | agg | x] bf16
  ushort_t* h2   = (ushort_t*)(ws + off);  off += (size_t)N * 2048 * 2;  // also reused as h7
  ushort_t* W1t = (ushort_t*)(ws + off);   off += (size_t)2048 * 512 * 2;
  ushort_t* W3t = (ushort_t*)(ws + off);   off += (size_t)2048 * 2048 * 2;
  ushort_t* W6t = (ushort_t*)(ws + off);   off += (size_t)2048 * 2560 * 2;
  ushort_t* W8t = (ushort_t*)(ws + off);   off += (size_t)512 * 2048 * 2;
  int* deg    = (int*)(ws + off);  off += (size_t)N * 4;
  int* startp = (int*)(ws + off);  off += (size_t)N * 4;
  int* cursor = (int*)(ws + off);  off += (size_t)N * 4;
  int* eids   = (int*)(ws + off);  off += (size_t)E * 4;

  hipMemsetAsync(deg, 0, (size_t)N * 4, stream);

  transpose_w<<<dim3(512 / 32, 2048 / 32), 256, 0, stream>>>(W1, W1t, 512, 2048);
  transpose_w<<<dim3(2048 / 32, 2048 / 32), 256, 0, stream>>>(W3, W3t, 2048, 2048);
  transpose_w<<<dim3(2560 / 32, 2048 / 32), 256, 0, stream>>>(W6, W6t, 2560, 2048);
  transpose_w<<<dim3(2048 / 32, 512 / 32), 256, 0, stream>>>(W8, W8t, 2048, 512);

  // CSR build + gather-mean
  count_edges<<<(E + 255) / 256, 256, 0, stream>>>(col, deg, E);
  prefix_kernel<<<1, 1024, 0, stream>>>(deg, startp, cursor, N);
  fill_csr<<<(E + 255) / 256, 256, 0, stream>>>(col, cursor, eids, E);
  gather_mean<<<N, 256, 0, stream>>>(eattr, startp, deg, eids, x, hcat, N);

  const int Mt = (N + 127) / 128;   // 157
  // GEMM1: h0 [N,512] @ W1 -> h2 bf16 (ReLU)
  gemm128<1, 1><<<dim3(8, Mt), 512, 0, stream>>>(hcat + 2048, 2560, W1t, b1, h2, 2048, N, 512);
  // GEMM2: h2 @ W3 -> h4 bf16 (ReLU) DIRECTLY into hcat[:, 0:2048]
  gemm128<1, 1><<<dim3(8, Mt), 512, 0, stream>>>(h2, 2048, W3t, b3, hcat, 2560, N, 2048);
  // LN in place on hcat[:, 0:2048]
  ln_kernel<<<N, 256, 0, stream>>>(hcat, lng, lnb);
  // GEMM3: hcat [N,2560] @ W6 -> h7 bf16 (ReLU), reuse h2 buffer
  gemm128<1, 1><<<dim3(8, Mt), 512, 0, stream>>>(hcat, 2560, W6t, b6, h2, 2048, N, 2560);
  // GEMM4: h7 @ W8 -> out f32
  gemm128<0, 0><<<dim3(2, Mt), 512, 0, stream>>>(h2, 2048, W8t, b8, (float*)d_out, 512, N, 2048);
}

// Round 7
// 843.913 us; speedup vs baseline: 3.7763x; 1.0456x over previous
//
#include <hip/hip_runtime.h>

typedef unsigned short ushort_t;
typedef __attribute__((ext_vector_type(4))) float f32x4;
typedef __attribute__((ext_vector_type(8))) __bf16 bf16x8;
typedef __attribute__((ext_vector_type(8))) unsigned short u16x8;
typedef __attribute__((ext_vector_type(4))) unsigned short u16x4;

__device__ __forceinline__ unsigned short f2bf(float f) {
  union { float f; unsigned int u; } v; v.f = f;
  unsigned int u = v.u;
  u += 0x7fffu + ((u >> 16) & 1u);   // round-to-nearest-even
  return (unsigned short)(u >> 16);
}

__device__ __forceinline__ float bf2f(unsigned short h) {
  union { unsigned int u; float f; } v; v.u = ((unsigned int)h) << 16;
  return v.f;
}

__device__ __forceinline__ void gload16(ushort_t* lds, const ushort_t* g) {
  __builtin_amdgcn_global_load_lds(
      (const __attribute__((address_space(1))) unsigned int*)g,
      (__attribute__((address_space(3))) unsigned int*)lds, 16, 0, 0);
}

// ---------------- weight transpose + f32->bf16 convert:  in [R][C] f32 -> out [C][R] bf16
__global__ __launch_bounds__(256)
void transpose_w(const float* __restrict__ in, ushort_t* __restrict__ out, int R, int C) {
  __shared__ float tile[32][33];
  const int t = threadIdx.x;
  const int tx = t & 31, ty = t >> 5;
  const int r0 = blockIdx.x * 32, c0 = blockIdx.y * 32;
#pragma unroll
  for (int i = 0; i < 4; ++i)
    tile[ty + 8 * i][tx] = in[(size_t)(r0 + ty + 8 * i) * C + c0 + tx];
  __syncthreads();
#pragma unroll
  for (int i = 0; i < 4; ++i)
    out[(size_t)(c0 + ty + 8 * i) * R + r0 + tx] = f2bf(tile[tx][ty + 8 * i]);
}

// ---------------- CSR build: histogram, prefix scan, fill
__global__ __launch_bounds__(256)
void count_edges(const int* __restrict__ col, int* __restrict__ cnt, int E) {
  int i = blockIdx.x * 256 + threadIdx.x;
  if (i < E) atomicAdd(&cnt[col[i]], 1);
}

__global__ __launch_bounds__(1024)
void prefix_kernel(const int* __restrict__ cnt, int* __restrict__ start,
                   int* __restrict__ cursor, int N) {
  const int t = threadIdx.x;
  const int chunk = (N + 1023) >> 10;
  const int base = t * chunk;
  int s = 0;
  for (int j = 0; j < chunk; ++j) {
    int i = base + j;
    s += (i < N) ? cnt[i] : 0;
  }
  const int lane = t & 63, wv = t >> 6;
  int scan = s;
#pragma unroll
  for (int o = 1; o < 64; o <<= 1) {
    int up = __shfl_up(scan, o);
    if (lane >= o) scan += up;
  }
  __shared__ int wsum[16];
  if (lane == 63) wsum[wv] = scan;
  __syncthreads();
  if (t == 0) {
    int acc = 0;
#pragma unroll
    for (int i2 = 0; i2 < 16; ++i2) { int v = wsum[i2]; wsum[i2] = acc; acc += v; }
  }
  __syncthreads();
  int run = wsum[wv] + (scan - s);
  for (int j = 0; j < chunk; ++j) {
    int i = base + j;
    if (i < N) {
      start[i] = run; cursor[i] = run;
      run += cnt[i];
    }
  }
}

__global__ __launch_bounds__(256)
void fill_csr(const int* __restrict__ col, int* __restrict__ cursor,
              int* __restrict__ eids, int E) {
  int i = blockIdx.x * 256 + threadIdx.x;
  if (i < E) {
    int p = atomicAdd(&cursor[col[i]], 1);
    eids[p] = i;
  }
}

// ---------------- gather-mean + build h0: block/node, wave-per-edge, float4/lane
__global__ __launch_bounds__(256)
void gather_mean(const float* __restrict__ eattr, const int* __restrict__ start,
                 const int* __restrict__ deg, const int* __restrict__ eids,
                 const float* __restrict__ x, ushort_t* __restrict__ hcat, int N) {
  const int row = blockIdx.x;
  const int t = threadIdx.x;
  const int w = t >> 6, l = t & 63;
  const int s = start[row], d = deg[row];
  const float4* ea4 = (const float4*)eattr;
  float4 sum = make_float4(0.f, 0.f, 0.f, 0.f);
  for (int i = w; i < d; i += 4) {
    int e = eids[s + i];
    float4 v = ea4[(size_t)e * 64 + l];
    sum.x += v.x; sum.y += v.y; sum.z += v.z; sum.w += v.w;
  }
  __shared__ float4 part[4][64];
  part[w][l] = sum;
  __syncthreads();
  hcat[(size_t)row * 2560 + 2304 + t] = f2bf(x[(size_t)row * 256 + t]);
  if (w == 0) {
    float4 a = part[0][l], b = part[1][l], c = part[2][l], dd = part[3][l];
    const float inv = 1.f / fmaxf((float)d, 1.f);
    u16x4 o;
    o[0] = f2bf((a.x + b.x + c.x + dd.x) * inv);
    o[1] = f2bf((a.y + b.y + c.y + dd.y) * inv);
    o[2] = f2bf((a.z + b.z + c.z + dd.z) * inv);
    o[3] = f2bf((a.w + b.w + c.w + dd.w) * inv);
    *(u16x4*)(hcat + (size_t)row * 2560 + 2048 + l * 4) = o;
  }
}

// ---------------- LayerNorm IN PLACE over hcat[:, 0:2048] bf16 (row-local)
__global__ __launch_bounds__(256)
void ln_kernel(ushort_t* __restrict__ hcat, const float* __restrict__ g,
               const float* __restrict__ b) {
  const int row = blockIdx.x;
  const int t = threadIdx.x;
  ushort_t* p = hcat + (size_t)row * 2560 + t * 8;
  u16x8 raw = *(const u16x8*)p;
  float vv[8];
#pragma unroll
  for (int j = 0; j < 8; ++j) vv[j] = bf2f(raw[j]);
  float s = 0.f, ss = 0.f;
#pragma unroll
  for (int j = 0; j < 8; ++j) { s += vv[j]; ss += vv[j] * vv[j]; }
#pragma unroll
  for (int o = 32; o > 0; o >>= 1) {
    s += __shfl_xor(s, o);
    ss += __shfl_xor(ss, o);
  }
  __shared__ float red[8];
  int w = t >> 6, l = t & 63;
  if (l == 0) { red[w] = s; red[4 + w] = ss; }
  __syncthreads();
  s = red[0] + red[1] + red[2] + red[3];
  ss = red[4] + red[5] + red[6] + red[7];
  const float mu = s * (1.f / 2048.f);
  const float var = ss * (1.f / 2048.f) - mu * mu;
  const float rs = rsqrtf(var + 1e-5f);
  float4 g0 = *(const float4*)(g + t * 8);
  float4 g1 = *(const float4*)(g + t * 8 + 4);
  float4 b0 = *(const float4*)(b + t * 8);
  float4 b1 = *(const float4*)(b + t * 8 + 4);
  float gg[8] = {g0.x, g0.y, g0.z, g0.w, g1.x, g1.y, g1.z, g1.w};
  float bb[8] = {b0.x, b0.y, b0.z, b0.w, b1.x, b1.y, b1.z, b1.w};
  u16x8 o8;
#pragma unroll
  for (int j = 0; j < 8; ++j) o8[j] = f2bf((vv[j] - mu) * rs * gg[j] + bb[j]);
  *(u16x8*)p = o8;
}

// ======================= 128x256 8-wave GEMM, BK=32, 2 blocks/CU =======================
// 512 threads = 8 waves (2M x 4N), per-wave C = 64x64 (acc[4][4] = 64 VGPR).
// LDS: 3 bufs x (A 128x32 | B 256x32) bf16 = 72 KiB -> 2 blocks/CU.
// Single barrier + single counted vmcnt(3) per K-tile (ledger: barrier passage implies
// all waves lgkmcnt-drained their tile-k reads [reads precede MFMA precede barrier],
// so staging tile k+2 into buffer (k-1)%3 after the barrier cannot race; vmcnt(3)
// completes exactly tile k+1's 3 loads, leaving tile k+2's 3 in flight).
// SWAPPED MFMA OPERANDS: acc[m][n] = mfma(b[n], a[m], acc) -> per-lane acc f32x4 holds
// one M-row (lr) x 4 consecutive N-cols (lk*4+reg) => vectorized u16x4/float4 C-stores.

#define SBAR() do { __builtin_amdgcn_sched_barrier(0); \
                    __builtin_amdgcn_s_barrier(); \
                    __builtin_amdgcn_sched_barrier(0); } while (0)

template <int RELU, int OUTBF>
__global__ __launch_bounds__(512, 4)
void gemm128(const ushort_t* __restrict__ A, int lda,
             const ushort_t* __restrict__ Bt,
             const float* __restrict__ bias,
             void* __restrict__ Cout, int ldc, int M, int K) {
  __shared__ __align__(16) ushort_t smem[36864];  // 72 KiB = 3 x 24 KiB
  char* sb = (char*)smem;
  const int t = threadIdx.x;

  // block remap: col-fastest + bijective XCD chunks
  const int nct = gridDim.x;
  const int nwg = nct * gridDim.y;
  const int flat = blockIdx.y * nct + blockIdx.x;
  const int xcd = flat & 7, loc = flat >> 3;
  const int q = nwg >> 3, r = nwg & 7;
  const int swz = (xcd < r ? xcd * (q + 1) : r * (q + 1) + (xcd - r) * q) + loc;
  const int row0 = (swz / nct) * 128;
  const int col0 = (swz % nct) * 256;

  const int wid = t >> 6, l = t & 63;
  const int wr = wid >> 2, wc = wid & 3;   // 2 x 4 waves, per-wave 64x64
  const int lr = l & 15, lk = l >> 4;

  // ---- staging: thread t -> row t>>2 (0..127), 16B slot t&3; source col pre-swizzled
  const int srow = t >> 2;
  const int scol = ((t & 3) ^ ((t >> 2) & 3)) << 3;   // elems
  int ar = row0 + srow; if (ar > M - 1) ar = M - 1;
  const ushort_t* pa  = A + (size_t)ar * lda + scol;
  const ushort_t* pb0 = Bt + (size_t)(col0 + srow) * K + scol;
  const ushort_t* pb1 = pb0 + (size_t)128 * K;
  const int tb = t * 16;

  // ---- reader offsets: row pitch 64B, slot xor (row&3) == (lr&3)
  const int sx = ((lk ^ (lr & 3)) << 4);
  const int arow = (wr * 64 + lr) * 64 + sx;            // + m*1024
  const int brow = 8192 + (wc * 64 + lr) * 64 + sx;     // + n*1024

  f32x4 acc[4][4] = {};

  const int nk = K >> 5;

  // ---- prologue: tile0 {B0,B1,A}, tile1 {B0,B1,A}; drain to tile0 (vmcnt(3))
  {
    const int k1 = (nk > 1) ? 32 : 0;
    gload16((ushort_t*)(sb + 8192 + tb), pb0);
    gload16((ushort_t*)(sb + 16384 + tb), pb1);
    gload16((ushort_t*)(sb + 0 + tb), pa);
    gload16((ushort_t*)(sb + 24576 + 8192 + tb), pb0 + k1);
    gload16((ushort_t*)(sb + 24576 + 16384 + tb), pb1 + k1);
    gload16((ushort_t*)(sb + 24576 + 0 + tb), pa + k1);
  }
  asm volatile("s_waitcnt vmcnt(3)" ::: "memory");
  SBAR();

  int cO = 0, sO = 49152;  // current buf, stage buf = (k+2)%3
  for (int k = 0; k < nk; ++k) {
    const int kc2 = ((k + 2 < nk) ? k + 2 : nk - 1) << 5;  // elem offset

    bf16x8 a[4], b[4];
#pragma unroll
    for (int m = 0; m < 4; ++m)
      a[m] = *(const bf16x8*)(sb + cO + arow + m * 1024);
#pragma unroll
    for (int n = 0; n < 4; ++n)
      b[n] = *(const bf16x8*)(sb + cO + brow + n * 1024);
    gload16((ushort_t*)(sb + sO + 8192 + tb), pb0 + kc2);
    gload16((ushort_t*)(sb + sO + 16384 + tb), pb1 + kc2);
    gload16((ushort_t*)(sb + sO + 0 + tb), pa + kc2);

    __builtin_amdgcn_s_setprio(1);
#pragma unroll
    for (int m = 0; m < 4; ++m)
#pragma unroll
      for (int n = 0; n < 4; ++n)
        acc[m][n] = __builtin_amdgcn_mfma_f32_16x16x32_bf16(b[n], a[m], acc[m][n], 0, 0, 0);
    __builtin_amdgcn_s_setprio(0);

    asm volatile("s_waitcnt vmcnt(3)" ::: "memory");
    SBAR();

    cO = (cO == 49152) ? 0 : cO + 24576;
    sO = (sO == 49152) ? 0 : sO + 24576;
  }
  asm volatile("s_waitcnt vmcnt(0)" ::: "memory");  // retire dangling prefetches

  // ---- epilogue: swapped layout -> per-lane row (lr) x 4 consecutive cols (lk*4+reg)
#pragma unroll
  for (int mi = 0; mi < 4; ++mi) {
    const int orow = row0 + wr * 64 + mi * 16 + lr;
    if (orow < M) {
#pragma unroll
      for (int nj = 0; nj < 4; ++nj) {
        const int cb = col0 + wc * 64 + nj * 16 + lk * 4;
        const float4 bv = *(const float4*)(bias + cb);
        f32x4 v = acc[mi][nj];
        float o0 = v[0] + bv.x, o1 = v[1] + bv.y, o2 = v[2] + bv.z, o3 = v[3] + bv.w;
        if (RELU) {
          o0 = fmaxf(o0, 0.f); o1 = fmaxf(o1, 0.f);
          o2 = fmaxf(o2, 0.f); o3 = fmaxf(o3, 0.f);
        }
        if (OUTBF) {
          u16x4 o;
          o[0] = f2bf(o0); o[1] = f2bf(o1); o[2] = f2bf(o2); o[3] = f2bf(o3);
          *(u16x4*)((ushort_t*)Cout + (size_t)orow * ldc + cb) = o;
        } else {
          float4 ov = make_float4(o0, o1, o2, o3);
          *(float4*)((float*)Cout + (size_t)orow * ldc + cb) = ov;
        }
      }
    }
  }
}

extern "C" void kernel_launch(void* const* d_in, const int* in_sizes, int n_in,
                              void* d_out, int out_size, void* d_ws, size_t ws_size,
                              hipStream_t stream) {
  (void)n_in; (void)out_size; (void)ws_size;
  const float* x     = (const float*)d_in[0];
  const int*   eidx  = (const int*)d_in[1];
  const float* eattr = (const float*)d_in[2];
  const float* W1 = (const float*)d_in[6];
  const float* b1 = (const float*)d_in[7];
  const float* W3 = (const float*)d_in[8];
  const float* b3 = (const float*)d_in[9];
  const float* lng = (const float*)d_in[10];
  const float* lnb = (const float*)d_in[11];
  const float* W6 = (const float*)d_in[12];
  const float* b6 = (const float*)d_in[13];
  const float* W8 = (const float*)d_in[14];
  const float* b8 = (const float*)d_in[15];

  const int N = in_sizes[0] / 256;  // 20000
  const int E = in_sizes[2] / 256;  // 640000
  const int* col = eidx + E;        // edge_index[1]

  char* ws = (char*)d_ws;
  size_t off = 0;
  ushort_t* hcat = (ushort_t*)(ws + off);  off += (size_t)N * 2560 * 2;  // [h5/h4 | agg | x] bf16
  ushort_t* h2   = (ushort_t*)(ws + off);  off += (size_t)N * 2048 * 2;  // also reused as h7
  ushort_t* W1t = (ushort_t*)(ws + off);   off += (size_t)2048 * 512 * 2;
  ushort_t* W3t = (ushort_t*)(ws + off);   off += (size_t)2048 * 2048 * 2;
  ushort_t* W6t = (ushort_t*)(ws + off);   off += (size_t)2048 * 2560 * 2;
  ushort_t* W8t = (ushort_t*)(ws + off);   off += (size_t)512 * 2048 * 2;
  int* deg    = (int*)(ws + off);  off += (size_t)N * 4;
  int* startp = (int*)(ws + off);  off += (size_t)N * 4;
  int* cursor = (int*)(ws + off);  off += (size_t)N * 4;
  int* eids   = (int*)(ws + off);  off += (size_t)E * 4;

  hipMemsetAsync(deg, 0, (size_t)N * 4, stream);

  transpose_w<<<dim3(512 / 32, 2048 / 32), 256, 0, stream>>>(W1, W1t, 512, 2048);
  transpose_w<<<dim3(2048 / 32, 2048 / 32), 256, 0, stream>>>(W3, W3t, 2048, 2048);
  transpose_w<<<dim3(2560 / 32, 2048 / 32), 256, 0, stream>>>(W6, W6t, 2560, 2048);
  transpose_w<<<dim3(2048 / 32, 512 / 32), 256, 0, stream>>>(W8, W8t, 2048, 512);

  // CSR build + gather-mean
  count_edges<<<(E + 255) / 256, 256, 0, stream>>>(col, deg, E);
  prefix_kernel<<<1, 1024, 0, stream>>>(deg, startp, cursor, N);
  fill_csr<<<(E + 255) / 256, 256, 0, stream>>>(col, cursor, eids, E);
  gather_mean<<<N, 256, 0, stream>>>(eattr, startp, deg, eids, x, hcat, N);

  const int Mt = (N + 127) / 128;   // 157
  // GEMM1: h0 [N,512] @ W1 -> h2 bf16 (ReLU)
  gemm128<1, 1><<<dim3(8, Mt), 512, 0, stream>>>(hcat + 2048, 2560, W1t, b1, h2, 2048, N, 512);
  // GEMM2: h2 @ W3 -> h4 bf16 (ReLU) DIRECTLY into hcat[:, 0:2048]
  gemm128<1, 1><<<dim3(8, Mt), 512, 0, stream>>>(h2, 2048, W3t, b3, hcat, 2560, N, 2048);
  // LN in place on hcat[:, 0:2048]
  ln_kernel<<<N, 256, 0, stream>>>(hcat, lng, lnb);
  // GEMM3: hcat [N,2560] @ W6 -> h7 bf16 (ReLU), reuse h2 buffer
  gemm128<1, 1><<<dim3(8, Mt), 512, 0, stream>>>(hcat, 2560, W6t, b6, h2, 2048, N, 2560);
  // GEMM4: h7 @ W8 -> out f32
  gemm128<0, 0><<<dim3(2, Mt), 512, 0, stream>>>(h2, 2048, W8t, b8, (float*)d_out, 512, N, 2048);
}